// Round 4
// baseline (316.083 us; speedup 1.0000x reference)
//
#include <hip/hip_runtime.h>
#include <hip/hip_bf16.h>

#define NB 16
#define DMODEL 1024
#define HALFD 512
#define PNUM 4096
#define PLEN 32
#define SEQ 2048
#define SIM 64
#define NPATCH 64
#define NROWS (NB*SEQ)        // 32768 sequence rows
#define MROWS (NB*NPATCH)     // 1024 (b,p) rows
#define KDIM (PLEN*HALFD)     // 16384
#define KSPLIT 8
#define MTILES 16
#define OUT0 ((size_t)NB*SEQ*DMODEL)

// ---------------- K0: gp_w row means + gp_b mean (fp64) ----------------
__global__ void k_prep(const float* __restrict__ gp_w, const float* __restrict__ gp_b,
                       double* __restrict__ gpw_mean) {
    int h = threadIdx.x;                       // 512 threads
    double s = 0.0;
    #pragma unroll
    for (int j = 0; j < 10; ++j) s += (double)gp_w[h*10 + j];
    gpw_mean[h] = s / 10.0;
    if (h == 0) {
        double sb = 0.0;
        #pragma unroll
        for (int j = 0; j < 10; ++j) sb += (double)gp_b[j];
        gpw_mean[HALFD] = sb / 10.0;           // gpb_mean at [512]
    }
}

// ---------------- K1: copy first half + low dot (fp64 accumulate) ----------------
__global__ __launch_bounds__(256) void k_copy_low(
        const float* __restrict__ src, const double* __restrict__ gpw_mean,
        float* __restrict__ out, double* __restrict__ low) {
    int wave = (blockIdx.x * 256 + threadIdx.x) >> 6;   // one wave per row
    int lane = threadIdx.x & 63;
    const float4* s4 = reinterpret_cast<const float4*>(src + (size_t)wave * DMODEL);
    float4 c0 = s4[lane];
    float4 c1 = s4[lane + 64];
    float4* o4 = reinterpret_cast<float4*>(out + (size_t)wave * DMODEL);
    o4[lane]      = c0;
    o4[lane + 64] = c1;
    // low = dot(second half, gpw_mean) + gpb_mean   -- fp64
    float4 x0 = s4[128 + lane];
    float4 x1 = s4[192 + lane];
    const double* g0 = gpw_mean + lane*4;
    const double* g1 = gpw_mean + 256 + lane*4;
    double d = (double)x0.x*g0[0] + (double)x0.y*g0[1] + (double)x0.z*g0[2] + (double)x0.w*g0[3]
             + (double)x1.x*g1[0] + (double)x1.y*g1[1] + (double)x1.z*g1[2] + (double)x1.w*g1[3];
    #pragma unroll
    for (int o = 32; o; o >>= 1) d += __shfl_xor(d, o);
    if (lane == 0) low[wave] = d + gpw_mean[HALFD];
}

// ---------------- K2: 1-wave-per-patch register-resident top-64 ----------------
// lane holds scores for n = j*64 + lane, j=0..63 (fp64, exact ranking).
// Extraction: shfl butterfly argmax on (val, n), lowest n wins ties; winner
// lane marks removal bit and rescans its 64 regs (statically unrolled).
__global__ __launch_bounds__(64) void k_topk(
        const double* __restrict__ low, const float* __restrict__ pool,
        int* __restrict__ sel) {
    __shared__ double lowp[PLEN];
    int p = blockIdx.x, lane = threadIdx.x;
    if (lane < PLEN) lowp[lane] = low[p*PLEN + lane];
    __syncthreads();
    double sc[64];
    #pragma unroll
    for (int j = 0; j < 64; ++j) {
        const float4* p4 = reinterpret_cast<const float4*>(pool + (size_t)(j*64 + lane)*PLEN);
        double s = 0.0;
        #pragma unroll
        for (int q = 0; q < 8; ++q) {
            float4 v = p4[q];
            s += (double)v.x*lowp[q*4] + (double)v.y*lowp[q*4+1]
               + (double)v.z*lowp[q*4+2] + (double)v.w*lowp[q*4+3];
        }
        sc[j] = s;
    }
    unsigned long long removed = 0ull;
    double lv = sc[0]; int lj = 0;
    #pragma unroll
    for (int j = 1; j < 64; ++j) { if (sc[j] > lv) { lv = sc[j]; lj = j; } }
    for (int s = 0; s < SIM; ++s) {
        double bv = lv; int bn = lj*64 + lane;
        #pragma unroll
        for (int o = 32; o; o >>= 1) {
            double ov = __shfl_xor(bv, o);
            int on = __shfl_xor(bn, o);
            if (ov > bv || (ov == bv && on < bn)) { bv = ov; bn = on; }
        }
        if (lane == 0) sel[p*SIM + s] = bn;
        if (bn == lj*64 + lane) {              // this lane's entry was taken
            removed |= (1ull << lj);
            double nv = -1.0e300; int nj = 0;
            #pragma unroll
            for (int j = 0; j < 64; ++j) {
                bool alive = ((removed >> j) & 1ull) == 0ull;
                if (alive && sc[j] > nv) { nv = sc[j]; nj = j; }
            }
            lv = nv; lj = nj;
        }
    }
}

// ---------------- K3: logits GEMM partials (M=1024,K=16384,N=64), K-split x8 ----------------
__global__ __launch_bounds__(256) void k_logits(
        const float* __restrict__ src, const float* __restrict__ fw,
        float* __restrict__ part) {
    __shared__ float xsT[64][68];              // [k][row] transposed, pad 68
    __shared__ float wsm[64][68];              // [k][n]
    int mt = blockIdx.x, ks = blockIdx.y;
    int t = threadIdx.x;
    int r0 = mt * 64;
    int ty = t >> 4, tx = t & 15;
    float acc[4][4] = {};
    for (int kc = 0; kc < KDIM/KSPLIT; kc += 64) {
        int k0 = ks * (KDIM/KSPLIT) + kc;
        int l = k0 >> 9, h0 = k0 & 511;        // 64-chunk never crosses l boundary
        {   // x tile -> transposed store
            int i = t >> 2;
            int row = r0 + i;
            int b = row >> 6, p = row & 63;
            const float* srow = src + ((size_t)(b*SEQ + p*PLEN + l)) * DMODEL + HALFD + h0;
            #pragma unroll
            for (int q = 0; q < 4; ++q) {
                int kk = (t & 3)*4 + q*16;
                float4 v = *reinterpret_cast<const float4*>(srow + kk);
                xsT[kk+0][i] = v.x; xsT[kk+1][i] = v.y;
                xsT[kk+2][i] = v.z; xsT[kk+3][i] = v.w;
            }
        }
        {   // w tile
            int j = t >> 2;
            const float* wrow = fw + (size_t)(k0 + j) * SIM;
            #pragma unroll
            for (int q = 0; q < 4; ++q) {
                int f4 = (t & 3) + q*4;
                float4 v = *reinterpret_cast<const float4*>(wrow + f4*4);
                *reinterpret_cast<float4*>(&wsm[j][f4*4]) = v;
            }
        }
        __syncthreads();
        #pragma unroll 8
        for (int k = 0; k < 64; ++k) {
            float4 av = *reinterpret_cast<float4*>(&xsT[k][ty*4]);
            float4 wv = *reinterpret_cast<float4*>(&wsm[k][tx*4]);
            acc[0][0] += av.x*wv.x; acc[0][1] += av.x*wv.y; acc[0][2] += av.x*wv.z; acc[0][3] += av.x*wv.w;
            acc[1][0] += av.y*wv.x; acc[1][1] += av.y*wv.y; acc[1][2] += av.y*wv.z; acc[1][3] += av.y*wv.w;
            acc[2][0] += av.z*wv.x; acc[2][1] += av.z*wv.y; acc[2][2] += av.z*wv.z; acc[2][3] += av.z*wv.w;
            acc[3][0] += av.w*wv.x; acc[3][1] += av.w*wv.y; acc[3][2] += av.w*wv.z; acc[3][3] += av.w*wv.w;
        }
        __syncthreads();
    }
    float* pp = part + ((size_t)(mt*KSPLIT + ks)) * 4096;
    #pragma unroll
    for (int i = 0; i < 4; ++i) {
        float4 v = { acc[i][0], acc[i][1], acc[i][2], acc[i][3] };
        *reinterpret_cast<float4*>(pp + (ty*4 + i)*64 + tx*4) = v;
    }
}

// ---------------- K4: reduce partials + bias + softmax -> route ----------------
__global__ __launch_bounds__(64) void k_softmax(
        const float* __restrict__ part, const float* __restrict__ fb,
        float* __restrict__ route) {
    int row = blockIdx.x;             // b*64+p
    int s = threadIdx.x;              // 0..63
    int mt = row >> 6, i = row & 63;
    float v = fb[s];
    #pragma unroll
    for (int ks = 0; ks < KSPLIT; ++ks)
        v += part[((size_t)(mt*KSPLIT + ks))*4096 + i*64 + s];
    float m = v;
    #pragma unroll
    for (int o = 32; o; o >>= 1) m = fmaxf(m, __shfl_xor(m, o));
    float e = expf(v - m);
    float sum = e;
    #pragma unroll
    for (int o = 32; o; o >>= 1) sum += __shfl_xor(sum, o);
    route[row*64 + s] = e / sum;
}

// ---------------- K5: fuse + recover GEMM + padding + zeros ----------------
__global__ __launch_bounds__(256) void k_out(
        const float* __restrict__ route, const int* __restrict__ sel,
        const float* __restrict__ pool, const float* __restrict__ rw,
        const float* __restrict__ rb, float* __restrict__ out, float* __restrict__ pad) {
    __shared__ float A_T[SIM][36];           // [s][l], pad 36
    __shared__ float rws[64][132];           // 128-col chunk of recover_w (+pad)
    __shared__ float routeS[64];
    int row = blockIdx.x;                    // b*64+p
    int b = row >> 6, p = row & 63;
    int t = threadIdx.x;
    if (t < 64) routeS[t] = route[row*64 + t];
    __syncthreads();
    #pragma unroll
    for (int q = 0; q < 8; ++q) {            // A_T[s][l] = route[s]*pool[sel[p,s]][l]
        int e = t + q*256;
        int s = e >> 5, l = e & 31;
        A_T[s][l] = routeS[s] * pool[(size_t)sel[p*SIM + s]*PLEN + l];
    }
    __syncthreads();
    if (t < 32) {                            // padding row-sum
        float ps = 0.f;
        #pragma unroll
        for (int s = 0; s < 64; ++s) ps += A_T[s][t];
        pad[(size_t)b*2*SEQ + SEQ + p*PLEN + t] = ps;
    } else if (t < 64) {                     // zeros in first half of padding_out
        pad[(size_t)b*2*SEQ + p*PLEN + (t - 32)] = 0.f;
    }
    int l0  = (t >> 5) * 4;
    int h04 = (t & 31) * 4;
    for (int hc = 0; hc < HALFD; hc += 128) {
        #pragma unroll
        for (int q = 0; q < 8; ++q) {        // stage recover_w[:, hc:hc+128]
            int fi = t + q*256;
            int r = fi >> 5, c4 = fi & 31;
            float4 v = *reinterpret_cast<const float4*>(rw + (size_t)r*HALFD + hc + c4*4);
            *reinterpret_cast<float4*>(&rws[r][c4*4]) = v;
        }
        __syncthreads();
        float acc[4][4] = {};
        #pragma unroll 8
        for (int s = 0; s < 64; ++s) {
            float4 av = *reinterpret_cast<float4*>(&A_T[s][l0]);
            float4 wv = *reinterpret_cast<float4*>(&rws[s][h04]);
            acc[0][0] += av.x*wv.x; acc[0][1] += av.x*wv.y; acc[0][2] += av.x*wv.z; acc[0][3] += av.x*wv.w;
            acc[1][0] += av.y*wv.x; acc[1][1] += av.y*wv.y; acc[1][2] += av.y*wv.z; acc[1][3] += av.y*wv.w;
            acc[2][0] += av.z*wv.x; acc[2][1] += av.z*wv.y; acc[2][2] += av.z*wv.z; acc[2][3] += av.z*wv.w;
            acc[3][0] += av.w*wv.x; acc[3][1] += av.w*wv.y; acc[3][2] += av.w*wv.z; acc[3][3] += av.w*wv.w;
        }
        int h = hc + h04;
        float4 bias = *reinterpret_cast<const float4*>(rb + h);
        #pragma unroll
        for (int i = 0; i < 4; ++i) {
            int l = l0 + i;
            float4 v = { acc[i][0] + bias.x, acc[i][1] + bias.y,
                         acc[i][2] + bias.z, acc[i][3] + bias.w };
            *reinterpret_cast<float4*>(out + ((size_t)(b*SEQ + p*PLEN + l))*DMODEL + HALFD + h) = v;
        }
        __syncthreads();
    }
}

static const void* by_size(void* const* d_in, const int* in_sizes, int n_in,
                           int want, int fallback) {
    for (int i = 0; i < n_in; ++i) if (in_sizes[i] == want) return d_in[i];
    return d_in[fallback];
}

extern "C" void kernel_launch(void* const* d_in, const int* in_sizes, int n_in,
                              void* d_out, int out_size, void* d_ws, size_t ws_size,
                              hipStream_t stream) {
    const float* src  = (const float*)by_size(d_in, in_sizes, n_in, NB*SEQ*DMODEL, 0);
    const float* pool = (const float*)by_size(d_in, in_sizes, n_in, PNUM*PLEN, 1);
    const float* fw   = (const float*)by_size(d_in, in_sizes, n_in, KDIM*SIM, 2);
    const float* fb   = (const float*)by_size(d_in, in_sizes, n_in, SIM, 3);
    const float* rw   = (const float*)by_size(d_in, in_sizes, n_in, SIM*HALFD, 4);
    const float* rb   = (const float*)by_size(d_in, in_sizes, n_in, HALFD, 5);
    const float* gpw  = (const float*)by_size(d_in, in_sizes, n_in, HALFD*10, 6);
    const float* gpb  = (const float*)by_size(d_in, in_sizes, n_in, 10, 7);
    float* out = (float*)d_out;
    float* pad = out + OUT0;

    double* gpw_mean = (double*)d_ws;                       // 513 doubles (pad to 1024)
    double* low      = gpw_mean + 1024;                     // 32768 doubles
    int*    sel      = (int*)(low + 32768);                 // 4096 ints
    float*  part     = (float*)(sel + 4096);                // 16*8*4096 floats = 2MB
    float*  route    = part + (size_t)MTILES*KSPLIT*4096;   // 65536 floats

    hipLaunchKernelGGL(k_prep,     dim3(1),          dim3(512), 0, stream, gpw, gpb, gpw_mean);
    hipLaunchKernelGGL(k_copy_low, dim3(NROWS/4),    dim3(256), 0, stream, src, gpw_mean, out, low);
    hipLaunchKernelGGL(k_topk,     dim3(NPATCH),     dim3(64),  0, stream, low, pool, sel);
    hipLaunchKernelGGL(k_logits,   dim3(MTILES, KSPLIT), dim3(256), 0, stream, src, fw, part);
    hipLaunchKernelGGL(k_softmax,  dim3(MROWS),      dim3(64),  0, stream, part, fb, route);
    hipLaunchKernelGGL(k_out,      dim3(MROWS),      dim3(256), 0, stream, route, sel, pool, rw, rb, out, pad);
}

// Round 5
// 260.061 us; speedup vs baseline: 1.2154x; 1.2154x over previous
//
#include <hip/hip_runtime.h>
#include <hip/hip_bf16.h>

#define NB 16
#define DMODEL 1024
#define HALFD 512
#define PNUM 4096
#define PLEN 32
#define SEQ 2048
#define SIM 64
#define NPATCH 64
#define NROWS (NB*SEQ)        // 32768 sequence rows
#define MROWS (NB*NPATCH)     // 1024 (b,p) rows
#define KDIM (PLEN*HALFD)     // 16384
#define KSPLIT 8
#define MTILES 16
#define OUT0 ((size_t)NB*SEQ*DMODEL)

// ---------------- K0: gp_w row means + gp_b mean (fp64) ----------------
__global__ void k_prep(const float* __restrict__ gp_w, const float* __restrict__ gp_b,
                       double* __restrict__ gpw_mean) {
    int h = threadIdx.x;                       // 512 threads
    double s = 0.0;
    #pragma unroll
    for (int j = 0; j < 10; ++j) s += (double)gp_w[h*10 + j];
    gpw_mean[h] = s / 10.0;
    if (h == 0) {
        double sb = 0.0;
        #pragma unroll
        for (int j = 0; j < 10; ++j) sb += (double)gp_b[j];
        gpw_mean[HALFD] = sb / 10.0;           // gpb_mean at [512]
    }
}

// ---------------- K1: copy first half + low dot (fp64 accumulate) ----------------
__global__ __launch_bounds__(256) void k_copy_low(
        const float* __restrict__ src, const double* __restrict__ gpw_mean,
        float* __restrict__ out, double* __restrict__ low) {
    int wave = (blockIdx.x * 256 + threadIdx.x) >> 6;   // one wave per row
    int lane = threadIdx.x & 63;
    const float4* s4 = reinterpret_cast<const float4*>(src + (size_t)wave * DMODEL);
    float4 c0 = s4[lane];
    float4 c1 = s4[lane + 64];
    float4* o4 = reinterpret_cast<float4*>(out + (size_t)wave * DMODEL);
    o4[lane]      = c0;
    o4[lane + 64] = c1;
    // low = dot(second half, gpw_mean) + gpb_mean   -- fp64
    float4 x0 = s4[128 + lane];
    float4 x1 = s4[192 + lane];
    const double* g0 = gpw_mean + lane*4;
    const double* g1 = gpw_mean + 256 + lane*4;
    double d = (double)x0.x*g0[0] + (double)x0.y*g0[1] + (double)x0.z*g0[2] + (double)x0.w*g0[3]
             + (double)x1.x*g1[0] + (double)x1.y*g1[1] + (double)x1.z*g1[2] + (double)x1.w*g1[3];
    #pragma unroll
    for (int o = 32; o; o >>= 1) d += __shfl_xor(d, o);
    if (lane == 0) low[wave] = d + gpw_mean[HALFD];
}

// ---------------- K2: top-64 per patch, LDS scores + 1-wave butterfly extraction ----------------
// 4 waves compute 4096 fp64 scores into LDS sc[j][l] (score of pattern n=j*64+l).
// Wave 0 extracts: per-lane running (max,argmax) over its column j=0..63; per round
// a 6-step shfl argmax (ties -> lowest global n), pop via -1e300 poison in LDS,
// cooperative column re-scan (lane l reads sc[l][wl]) to refresh winner's max.
__global__ __launch_bounds__(256) void k_topk(
        const double* __restrict__ low, const float* __restrict__ pool,
        int* __restrict__ sel) {
    __shared__ double sc[64][65];   // padded: 2-way max bank aliasing everywhere
    __shared__ double lowp[PLEN];
    int p = blockIdx.x, t = threadIdx.x;
    int lane = t & 63, wv = t >> 6;
    if (t < PLEN) lowp[t] = low[p*PLEN + t];
    __syncthreads();
    #pragma unroll
    for (int jj = 0; jj < 16; ++jj) {       // wave wv computes j = wv*16 + jj
        int j = wv*16 + jj;
        const float4* p4 = reinterpret_cast<const float4*>(pool + (size_t)(j*64 + lane)*PLEN);
        double s = 0.0;
        #pragma unroll
        for (int q = 0; q < 8; ++q) {
            float4 v = p4[q];
            s += (double)v.x*lowp[q*4] + (double)v.y*lowp[q*4+1]
               + (double)v.z*lowp[q*4+2] + (double)v.w*lowp[q*4+3];
        }
        sc[j][lane] = s;
    }
    __syncthreads();
    if (wv != 0) return;
    // per-lane max over its column
    double lv = -1.0e300; int lj = 0;
    #pragma unroll
    for (int j = 0; j < 64; ++j) {
        double v = sc[j][lane];
        if (v > lv) { lv = v; lj = j; }
    }
    for (int s = 0; s < SIM; ++s) {
        double bv = lv; int bn = lj*64 + lane;      // global pattern idx
        #pragma unroll
        for (int o = 32; o; o >>= 1) {
            double ov = __shfl_xor(bv, o);
            int on = __shfl_xor(bn, o);
            if (ov > bv || (ov == bv && on < bn)) { bv = ov; bn = on; }
        }
        if (lane == 0) {
            sel[p*SIM + s] = bn;
            sc[bn >> 6][bn & 63] = -1.0e300;        // remove popped entry
        }
        int wl = bn & 63;                           // winner lane (column owner)
        double cv = sc[lane][wl];                   // lane reads entry j=lane of column wl
        int cj = lane;
        #pragma unroll
        for (int o = 32; o; o >>= 1) {
            double ov = __shfl_xor(cv, o);
            int oj = __shfl_xor(cj, o);
            if (ov > cv || (ov == cv && oj < cj)) { cv = ov; cj = oj; }
        }
        if (lane == wl) { lv = cv; lj = cj; }       // refresh winner's running max
    }
}

// ---------------- K3: logits GEMM partials (M=1024,K=16384,N=64), K-split x8 ----------------
__global__ __launch_bounds__(256) void k_logits(
        const float* __restrict__ src, const float* __restrict__ fw,
        float* __restrict__ part) {
    __shared__ float xsT[64][68];              // [k][row] transposed, pad 68
    __shared__ float wsm[64][68];              // [k][n]
    int mt = blockIdx.x, ks = blockIdx.y;
    int t = threadIdx.x;
    int r0 = mt * 64;
    int ty = t >> 4, tx = t & 15;
    float acc[4][4] = {};
    for (int kc = 0; kc < KDIM/KSPLIT; kc += 64) {
        int k0 = ks * (KDIM/KSPLIT) + kc;
        int l = k0 >> 9, h0 = k0 & 511;        // 64-chunk never crosses l boundary
        {   // x tile -> transposed store
            int i = t >> 2;
            int row = r0 + i;
            int b = row >> 6, p = row & 63;
            const float* srow = src + ((size_t)(b*SEQ + p*PLEN + l)) * DMODEL + HALFD + h0;
            #pragma unroll
            for (int q = 0; q < 4; ++q) {
                int kk = (t & 3)*4 + q*16;
                float4 v = *reinterpret_cast<const float4*>(srow + kk);
                xsT[kk+0][i] = v.x; xsT[kk+1][i] = v.y;
                xsT[kk+2][i] = v.z; xsT[kk+3][i] = v.w;
            }
        }
        {   // w tile
            int j = t >> 2;
            const float* wrow = fw + (size_t)(k0 + j) * SIM;
            #pragma unroll
            for (int q = 0; q < 4; ++q) {
                int f4 = (t & 3) + q*4;
                float4 v = *reinterpret_cast<const float4*>(wrow + f4*4);
                *reinterpret_cast<float4*>(&wsm[j][f4*4]) = v;
            }
        }
        __syncthreads();
        #pragma unroll 8
        for (int k = 0; k < 64; ++k) {
            float4 av = *reinterpret_cast<float4*>(&xsT[k][ty*4]);
            float4 wv = *reinterpret_cast<float4*>(&wsm[k][tx*4]);
            acc[0][0] += av.x*wv.x; acc[0][1] += av.x*wv.y; acc[0][2] += av.x*wv.z; acc[0][3] += av.x*wv.w;
            acc[1][0] += av.y*wv.x; acc[1][1] += av.y*wv.y; acc[1][2] += av.y*wv.z; acc[1][3] += av.y*wv.w;
            acc[2][0] += av.z*wv.x; acc[2][1] += av.z*wv.y; acc[2][2] += av.z*wv.z; acc[2][3] += av.z*wv.w;
            acc[3][0] += av.w*wv.x; acc[3][1] += av.w*wv.y; acc[3][2] += av.w*wv.z; acc[3][3] += av.w*wv.w;
        }
        __syncthreads();
    }
    float* pp = part + ((size_t)(mt*KSPLIT + ks)) * 4096;
    #pragma unroll
    for (int i = 0; i < 4; ++i) {
        float4 v = { acc[i][0], acc[i][1], acc[i][2], acc[i][3] };
        *reinterpret_cast<float4*>(pp + (ty*4 + i)*64 + tx*4) = v;
    }
}

// ---------------- K4: reduce partials + bias + softmax -> route ----------------
__global__ __launch_bounds__(64) void k_softmax(
        const float* __restrict__ part, const float* __restrict__ fb,
        float* __restrict__ route) {
    int row = blockIdx.x;             // b*64+p
    int s = threadIdx.x;              // 0..63
    int mt = row >> 6, i = row & 63;
    float v = fb[s];
    #pragma unroll
    for (int ks = 0; ks < KSPLIT; ++ks)
        v += part[((size_t)(mt*KSPLIT + ks))*4096 + i*64 + s];
    float m = v;
    #pragma unroll
    for (int o = 32; o; o >>= 1) m = fmaxf(m, __shfl_xor(m, o));
    float e = expf(v - m);
    float sum = e;
    #pragma unroll
    for (int o = 32; o; o >>= 1) sum += __shfl_xor(sum, o);
    route[row*64 + s] = e / sum;
}

// ---------------- K5: fuse + recover GEMM + padding + zeros ----------------
__global__ __launch_bounds__(256) void k_out(
        const float* __restrict__ route, const int* __restrict__ sel,
        const float* __restrict__ pool, const float* __restrict__ rw,
        const float* __restrict__ rb, float* __restrict__ out, float* __restrict__ pad) {
    __shared__ float A_T[SIM][36];           // [s][l], pad 36
    __shared__ float rws[64][132];           // 128-col chunk of recover_w (+pad)
    __shared__ float routeS[64];
    int row = blockIdx.x;                    // b*64+p
    int b = row >> 6, p = row & 63;
    int t = threadIdx.x;
    if (t < 64) routeS[t] = route[row*64 + t];
    __syncthreads();
    #pragma unroll
    for (int q = 0; q < 8; ++q) {            // A_T[s][l] = route[s]*pool[sel[p,s]][l]
        int e = t + q*256;
        int s = e >> 5, l = e & 31;
        A_T[s][l] = routeS[s] * pool[(size_t)sel[p*SIM + s]*PLEN + l];
    }
    __syncthreads();
    if (t < 32) {                            // padding row-sum
        float ps = 0.f;
        #pragma unroll
        for (int s = 0; s < 64; ++s) ps += A_T[s][t];
        pad[(size_t)b*2*SEQ + SEQ + p*PLEN + t] = ps;
    } else if (t < 64) {                     // zeros in first half of padding_out
        pad[(size_t)b*2*SEQ + p*PLEN + (t - 32)] = 0.f;
    }
    int l0  = (t >> 5) * 4;
    int h04 = (t & 31) * 4;
    for (int hc = 0; hc < HALFD; hc += 128) {
        #pragma unroll
        for (int q = 0; q < 8; ++q) {        // stage recover_w[:, hc:hc+128]
            int fi = t + q*256;
            int r = fi >> 5, c4 = fi & 31;
            float4 v = *reinterpret_cast<const float4*>(rw + (size_t)r*HALFD + hc + c4*4);
            *reinterpret_cast<float4*>(&rws[r][c4*4]) = v;
        }
        __syncthreads();
        float acc[4][4] = {};
        #pragma unroll 8
        for (int s = 0; s < 64; ++s) {
            float4 av = *reinterpret_cast<float4*>(&A_T[s][l0]);
            float4 wv = *reinterpret_cast<float4*>(&rws[s][h04]);
            acc[0][0] += av.x*wv.x; acc[0][1] += av.x*wv.y; acc[0][2] += av.x*wv.z; acc[0][3] += av.x*wv.w;
            acc[1][0] += av.y*wv.x; acc[1][1] += av.y*wv.y; acc[1][2] += av.y*wv.z; acc[1][3] += av.y*wv.w;
            acc[2][0] += av.z*wv.x; acc[2][1] += av.z*wv.y; acc[2][2] += av.z*wv.z; acc[2][3] += av.z*wv.w;
            acc[3][0] += av.w*wv.x; acc[3][1] += av.w*wv.y; acc[3][2] += av.w*wv.z; acc[3][3] += av.w*wv.w;
        }
        int h = hc + h04;
        float4 bias = *reinterpret_cast<const float4*>(rb + h);
        #pragma unroll
        for (int i = 0; i < 4; ++i) {
            int l = l0 + i;
            float4 v = { acc[i][0] + bias.x, acc[i][1] + bias.y,
                         acc[i][2] + bias.z, acc[i][3] + bias.w };
            *reinterpret_cast<float4*>(out + ((size_t)(b*SEQ + p*PLEN + l))*DMODEL + HALFD + h) = v;
        }
        __syncthreads();
    }
}

static const void* by_size(void* const* d_in, const int* in_sizes, int n_in,
                           int want, int fallback) {
    for (int i = 0; i < n_in; ++i) if (in_sizes[i] == want) return d_in[i];
    return d_in[fallback];
}

extern "C" void kernel_launch(void* const* d_in, const int* in_sizes, int n_in,
                              void* d_out, int out_size, void* d_ws, size_t ws_size,
                              hipStream_t stream) {
    const float* src  = (const float*)by_size(d_in, in_sizes, n_in, NB*SEQ*DMODEL, 0);
    const float* pool = (const float*)by_size(d_in, in_sizes, n_in, PNUM*PLEN, 1);
    const float* fw   = (const float*)by_size(d_in, in_sizes, n_in, KDIM*SIM, 2);
    const float* fb   = (const float*)by_size(d_in, in_sizes, n_in, SIM, 3);
    const float* rw   = (const float*)by_size(d_in, in_sizes, n_in, SIM*HALFD, 4);
    const float* rb   = (const float*)by_size(d_in, in_sizes, n_in, HALFD, 5);
    const float* gpw  = (const float*)by_size(d_in, in_sizes, n_in, HALFD*10, 6);
    const float* gpb  = (const float*)by_size(d_in, in_sizes, n_in, 10, 7);
    float* out = (float*)d_out;
    float* pad = out + OUT0;

    double* gpw_mean = (double*)d_ws;                       // 513 doubles (pad to 1024)
    double* low      = gpw_mean + 1024;                     // 32768 doubles
    int*    sel      = (int*)(low + 32768);                 // 4096 ints
    float*  part     = (float*)(sel + 4096);                // 16*8*4096 floats = 2MB
    float*  route    = part + (size_t)MTILES*KSPLIT*4096;   // 65536 floats

    hipLaunchKernelGGL(k_prep,     dim3(1),          dim3(512), 0, stream, gpw, gpb, gpw_mean);
    hipLaunchKernelGGL(k_copy_low, dim3(NROWS/4),    dim3(256), 0, stream, src, gpw_mean, out, low);
    hipLaunchKernelGGL(k_topk,     dim3(NPATCH),     dim3(256), 0, stream, low, pool, sel);
    hipLaunchKernelGGL(k_logits,   dim3(MTILES, KSPLIT), dim3(256), 0, stream, src, fw, part);
    hipLaunchKernelGGL(k_softmax,  dim3(MROWS),      dim3(64),  0, stream, part, fb, route);
    hipLaunchKernelGGL(k_out,      dim3(MROWS),      dim3(256), 0, stream, route, sel, pool, rw, rb, out, pad);
}

// Round 6
// 196.735 us; speedup vs baseline: 1.6066x; 1.3219x over previous
//
#include <hip/hip_runtime.h>
#include <hip/hip_bf16.h>

#define NB 16
#define DMODEL 1024
#define HALFD 512
#define PNUM 4096
#define PLEN 32
#define SEQ 2048
#define SIM 64
#define NPATCH 64
#define NROWS (NB*SEQ)        // 32768 sequence rows
#define MROWS (NB*NPATCH)     // 1024 (b,p) rows
#define KDIM (PLEN*HALFD)     // 16384
#define KSPLIT 8
#define MTILES 16
#define OUT0 ((size_t)NB*SEQ*DMODEL)

// ---------------- K0: gp_w row means + gp_b mean (fp64) ----------------
__global__ void k_prep(const float* __restrict__ gp_w, const float* __restrict__ gp_b,
                       double* __restrict__ gpw_mean) {
    int h = threadIdx.x;                       // 512 threads
    double s = 0.0;
    #pragma unroll
    for (int j = 0; j < 10; ++j) s += (double)gp_w[h*10 + j];
    gpw_mean[h] = s / 10.0;
    if (h == 0) {
        double sb = 0.0;
        #pragma unroll
        for (int j = 0; j < 10; ++j) sb += (double)gp_b[j];
        gpw_mean[HALFD] = sb / 10.0;           // gpb_mean at [512]
    }
}

// ---------------- K1: copy first half + low dot (fp64 accumulate) ----------------
__global__ __launch_bounds__(256) void k_copy_low(
        const float* __restrict__ src, const double* __restrict__ gpw_mean,
        float* __restrict__ out, double* __restrict__ low) {
    int wave = (blockIdx.x * 256 + threadIdx.x) >> 6;   // one wave per row
    int lane = threadIdx.x & 63;
    const float4* s4 = reinterpret_cast<const float4*>(src + (size_t)wave * DMODEL);
    float4 c0 = s4[lane];
    float4 c1 = s4[lane + 64];
    float4* o4 = reinterpret_cast<float4*>(out + (size_t)wave * DMODEL);
    o4[lane]      = c0;
    o4[lane + 64] = c1;
    // low = dot(second half, gpw_mean) + gpb_mean   -- fp64
    float4 x0 = s4[128 + lane];
    float4 x1 = s4[192 + lane];
    const double* g0 = gpw_mean + lane*4;
    const double* g1 = gpw_mean + 256 + lane*4;
    double d = (double)x0.x*g0[0] + (double)x0.y*g0[1] + (double)x0.z*g0[2] + (double)x0.w*g0[3]
             + (double)x1.x*g1[0] + (double)x1.y*g1[1] + (double)x1.z*g1[2] + (double)x1.w*g1[3];
    #pragma unroll
    for (int o = 32; o; o >>= 1) d += __shfl_xor(d, o);
    if (lane == 0) low[wave] = d + gpw_mean[HALFD];
}

// ---------------- K2+K3 fused: logits GEMM (blocks 0..127) + top-64 (blocks 128..191) ----------------
// Top-k role: compute 4096 fp64 scores -> orderable uint64 keys, full bitonic
// sort (desc key, asc idx) in LDS, emit first 64. No serial extraction chain.
// Runs in the shadow of the logits blocks (1 block/CU, 192 blocks < 256 CUs).
union SharedU {
    struct { float xsT[64][68]; float wsm[64][68]; } g;                     // 34816 B
    struct { unsigned long long ky[PNUM]; unsigned short id[PNUM]; double lowp[PLEN]; } t; // 41216 B
};

__global__ __launch_bounds__(256) void k_logits_topk(
        const float* __restrict__ src, const float* __restrict__ fw,
        const float* __restrict__ pool, const double* __restrict__ low,
        float* __restrict__ part, int* __restrict__ sel) {
    __shared__ SharedU u;
    int t = threadIdx.x;
    if (blockIdx.x < 128) {
        // ---------------- logits role ----------------
        int mt = blockIdx.x >> 3, ks = blockIdx.x & 7;
        int r0 = mt * 64;
        int ty = t >> 4, tx = t & 15;
        float acc[4][4] = {};
        for (int kc = 0; kc < KDIM/KSPLIT; kc += 64) {
            int k0 = ks * (KDIM/KSPLIT) + kc;
            int l = k0 >> 9, h0 = k0 & 511;        // 64-chunk never crosses l boundary
            {   // x tile -> transposed store
                int i = t >> 2;
                int row = r0 + i;
                int b = row >> 6, p = row & 63;
                const float* srow = src + ((size_t)(b*SEQ + p*PLEN + l)) * DMODEL + HALFD + h0;
                #pragma unroll
                for (int q = 0; q < 4; ++q) {
                    int kk = (t & 3)*4 + q*16;
                    float4 v = *reinterpret_cast<const float4*>(srow + kk);
                    u.g.xsT[kk+0][i] = v.x; u.g.xsT[kk+1][i] = v.y;
                    u.g.xsT[kk+2][i] = v.z; u.g.xsT[kk+3][i] = v.w;
                }
            }
            {   // w tile
                int j = t >> 2;
                const float* wrow = fw + (size_t)(k0 + j) * SIM;
                #pragma unroll
                for (int q = 0; q < 4; ++q) {
                    int f4 = (t & 3) + q*4;
                    float4 v = *reinterpret_cast<const float4*>(wrow + f4*4);
                    *reinterpret_cast<float4*>(&u.g.wsm[j][f4*4]) = v;
                }
            }
            __syncthreads();
            #pragma unroll 8
            for (int k = 0; k < 64; ++k) {
                float4 av = *reinterpret_cast<float4*>(&u.g.xsT[k][ty*4]);
                float4 wv = *reinterpret_cast<float4*>(&u.g.wsm[k][tx*4]);
                acc[0][0] += av.x*wv.x; acc[0][1] += av.x*wv.y; acc[0][2] += av.x*wv.z; acc[0][3] += av.x*wv.w;
                acc[1][0] += av.y*wv.x; acc[1][1] += av.y*wv.y; acc[1][2] += av.y*wv.z; acc[1][3] += av.y*wv.w;
                acc[2][0] += av.z*wv.x; acc[2][1] += av.z*wv.y; acc[2][2] += av.z*wv.z; acc[2][3] += av.z*wv.w;
                acc[3][0] += av.w*wv.x; acc[3][1] += av.w*wv.y; acc[3][2] += av.w*wv.z; acc[3][3] += av.w*wv.w;
            }
            __syncthreads();
        }
        float* pp = part + ((size_t)(mt*KSPLIT + ks)) * 4096;
        #pragma unroll
        for (int i = 0; i < 4; ++i) {
            float4 v = { acc[i][0], acc[i][1], acc[i][2], acc[i][3] };
            *reinterpret_cast<float4*>(pp + (ty*4 + i)*64 + tx*4) = v;
        }
    } else {
        // ---------------- top-k role ----------------
        int p = blockIdx.x - 128;
        if (t < PLEN) u.t.lowp[t] = low[p*PLEN + t];   // batch-0 rows
        __syncthreads();
        #pragma unroll
        for (int q = 0; q < 16; ++q) {                 // scores + orderable keys
            int n = q*256 + t;
            const float4* p4 = reinterpret_cast<const float4*>(pool + (size_t)n*PLEN);
            double s = 0.0;
            #pragma unroll
            for (int r = 0; r < 8; ++r) {
                float4 v = p4[r];
                s += (double)v.x*u.t.lowp[r*4] + (double)v.y*u.t.lowp[r*4+1]
                   + (double)v.z*u.t.lowp[r*4+2] + (double)v.w*u.t.lowp[r*4+3];
            }
            unsigned long long ub = (unsigned long long)__double_as_longlong(s);
            unsigned long long key = ub ^ (((unsigned long long)((long long)ub >> 63)) | 0x8000000000000000ULL);
            u.t.ky[n] = key;
            u.t.id[n] = (unsigned short)n;
        }
        __syncthreads();
        // bitonic sort, best-first: descending key, ascending idx on ties
        for (int kk = 2; kk <= PNUM; kk <<= 1) {
            for (int j = kk >> 1; j > 0; j >>= 1) {
                #pragma unroll
                for (int e = 0; e < 8; ++e) {
                    int pi = e*256 + t;                        // 2048 disjoint pairs
                    int i  = ((pi & ~(j-1)) << 1) | (pi & (j-1));
                    int x  = i | j;
                    unsigned long long ka = u.t.ky[i], kb = u.t.ky[x];
                    unsigned short ia = u.t.id[i], ib = u.t.id[x];
                    bool up = (i & kk) == 0;
                    bool a_first = (ka > kb) || (ka == kb && ia < ib);
                    bool b_first = (kb > ka) || (kb == ka && ib < ia);
                    bool sw = up ? b_first : a_first;
                    if (sw) {
                        u.t.ky[i] = kb; u.t.ky[x] = ka;
                        u.t.id[i] = ib; u.t.id[x] = ia;
                    }
                }
                __syncthreads();
            }
        }
        if (t < SIM) sel[p*SIM + t] = (int)u.t.id[t];
    }
}

// ---------------- K4: reduce partials + bias + softmax -> route ----------------
__global__ __launch_bounds__(64) void k_softmax(
        const float* __restrict__ part, const float* __restrict__ fb,
        float* __restrict__ route) {
    int row = blockIdx.x;             // b*64+p
    int s = threadIdx.x;              // 0..63
    int mt = row >> 6, i = row & 63;
    float v = fb[s];
    #pragma unroll
    for (int ks = 0; ks < KSPLIT; ++ks)
        v += part[((size_t)(mt*KSPLIT + ks))*4096 + i*64 + s];
    float m = v;
    #pragma unroll
    for (int o = 32; o; o >>= 1) m = fmaxf(m, __shfl_xor(m, o));
    float e = expf(v - m);
    float sum = e;
    #pragma unroll
    for (int o = 32; o; o >>= 1) sum += __shfl_xor(sum, o);
    route[row*64 + s] = e / sum;
}

// ---------------- K5: fuse + recover GEMM + padding + zeros ----------------
__global__ __launch_bounds__(256) void k_out(
        const float* __restrict__ route, const int* __restrict__ sel,
        const float* __restrict__ pool, const float* __restrict__ rw,
        const float* __restrict__ rb, float* __restrict__ out, float* __restrict__ pad) {
    __shared__ float A_T[SIM][36];           // [s][l], pad 36
    __shared__ float rws[64][132];           // 128-col chunk of recover_w (+pad)
    __shared__ float routeS[64];
    int row = blockIdx.x;                    // b*64+p
    int b = row >> 6, p = row & 63;
    int t = threadIdx.x;
    if (t < 64) routeS[t] = route[row*64 + t];
    __syncthreads();
    #pragma unroll
    for (int q = 0; q < 8; ++q) {            // A_T[s][l] = route[s]*pool[sel[p,s]][l]
        int e = t + q*256;
        int s = e >> 5, l = e & 31;
        A_T[s][l] = routeS[s] * pool[(size_t)sel[p*SIM + s]*PLEN + l];
    }
    __syncthreads();
    if (t < 32) {                            // padding row-sum
        float ps = 0.f;
        #pragma unroll
        for (int s = 0; s < 64; ++s) ps += A_T[s][t];
        pad[(size_t)b*2*SEQ + SEQ + p*PLEN + t] = ps;
    } else if (t < 64) {                     // zeros in first half of padding_out
        pad[(size_t)b*2*SEQ + p*PLEN + (t - 32)] = 0.f;
    }
    int l0  = (t >> 5) * 4;
    int h04 = (t & 31) * 4;
    for (int hc = 0; hc < HALFD; hc += 128) {
        #pragma unroll
        for (int q = 0; q < 8; ++q) {        // stage recover_w[:, hc:hc+128]
            int fi = t + q*256;
            int r = fi >> 5, c4 = fi & 31;
            float4 v = *reinterpret_cast<const float4*>(rw + (size_t)r*HALFD + hc + c4*4);
            *reinterpret_cast<float4*>(&rws[r][c4*4]) = v;
        }
        __syncthreads();
        float acc[4][4] = {};
        #pragma unroll 8
        for (int s = 0; s < 64; ++s) {
            float4 av = *reinterpret_cast<float4*>(&A_T[s][l0]);
            float4 wv = *reinterpret_cast<float4*>(&rws[s][h04]);
            acc[0][0] += av.x*wv.x; acc[0][1] += av.x*wv.y; acc[0][2] += av.x*wv.z; acc[0][3] += av.x*wv.w;
            acc[1][0] += av.y*wv.x; acc[1][1] += av.y*wv.y; acc[1][2] += av.y*wv.z; acc[1][3] += av.y*wv.w;
            acc[2][0] += av.z*wv.x; acc[2][1] += av.z*wv.y; acc[2][2] += av.z*wv.z; acc[2][3] += av.z*wv.w;
            acc[3][0] += av.w*wv.x; acc[3][1] += av.w*wv.y; acc[3][2] += av.w*wv.z; acc[3][3] += av.w*wv.w;
        }
        int h = hc + h04;
        float4 bias = *reinterpret_cast<const float4*>(rb + h);
        #pragma unroll
        for (int i = 0; i < 4; ++i) {
            int l = l0 + i;
            float4 v = { acc[i][0] + bias.x, acc[i][1] + bias.y,
                         acc[i][2] + bias.z, acc[i][3] + bias.w };
            *reinterpret_cast<float4*>(out + ((size_t)(b*SEQ + p*PLEN + l))*DMODEL + HALFD + h) = v;
        }
        __syncthreads();
    }
}

static const void* by_size(void* const* d_in, const int* in_sizes, int n_in,
                           int want, int fallback) {
    for (int i = 0; i < n_in; ++i) if (in_sizes[i] == want) return d_in[i];
    return d_in[fallback];
}

extern "C" void kernel_launch(void* const* d_in, const int* in_sizes, int n_in,
                              void* d_out, int out_size, void* d_ws, size_t ws_size,
                              hipStream_t stream) {
    const float* src  = (const float*)by_size(d_in, in_sizes, n_in, NB*SEQ*DMODEL, 0);
    const float* pool = (const float*)by_size(d_in, in_sizes, n_in, PNUM*PLEN, 1);
    const float* fw   = (const float*)by_size(d_in, in_sizes, n_in, KDIM*SIM, 2);
    const float* fb   = (const float*)by_size(d_in, in_sizes, n_in, SIM, 3);
    const float* rw   = (const float*)by_size(d_in, in_sizes, n_in, SIM*HALFD, 4);
    const float* rb   = (const float*)by_size(d_in, in_sizes, n_in, HALFD, 5);
    const float* gpw  = (const float*)by_size(d_in, in_sizes, n_in, HALFD*10, 6);
    const float* gpb  = (const float*)by_size(d_in, in_sizes, n_in, 10, 7);
    float* out = (float*)d_out;
    float* pad = out + OUT0;

    double* gpw_mean = (double*)d_ws;                       // 513 doubles (pad to 1024)
    double* low      = gpw_mean + 1024;                     // 32768 doubles
    int*    sel      = (int*)(low + 32768);                 // 4096 ints
    float*  part     = (float*)(sel + 4096);                // 16*8*4096 floats = 2MB
    float*  route    = part + (size_t)MTILES*KSPLIT*4096;   // 65536 floats

    hipLaunchKernelGGL(k_prep,        dim3(1),        dim3(512), 0, stream, gpw, gpb, gpw_mean);
    hipLaunchKernelGGL(k_copy_low,    dim3(NROWS/4),  dim3(256), 0, stream, src, gpw_mean, out, low);
    hipLaunchKernelGGL(k_logits_topk, dim3(192),      dim3(256), 0, stream, src, fw, pool, low, part, sel);
    hipLaunchKernelGGL(k_softmax,     dim3(MROWS),    dim3(64),  0, stream, part, fb, route);
    hipLaunchKernelGGL(k_out,         dim3(MROWS),    dim3(256), 0, stream, route, sel, pool, rw, rb, out, pad);
}

// Round 7
// 194.919 us; speedup vs baseline: 1.6216x; 1.0093x over previous
//
#include <hip/hip_runtime.h>
#include <hip/hip_bf16.h>

#define NB 16
#define DMODEL 1024
#define HALFD 512
#define PNUM 4096
#define PLEN 32
#define SEQ 2048
#define SIM 64
#define NPATCH 64
#define NROWS (NB*SEQ)        // 32768 sequence rows
#define MROWS (NB*NPATCH)     // 1024 (b,p) rows
#define KDIM (PLEN*HALFD)     // 16384
#define OUT0 ((size_t)NB*SEQ*DMODEL)
#define KIDX(i) ((i) + ((i) >> 3))   // bitonic LDS padding: breaks small-j bank conflicts

// ---------------- K0: gp_w row means + gp_b mean (fp64) ----------------
__global__ void k_prep(const float* __restrict__ gp_w, const float* __restrict__ gp_b,
                       double* __restrict__ gpw_mean) {
    int h = threadIdx.x;                       // 512 threads
    double s = 0.0;
    #pragma unroll
    for (int j = 0; j < 10; ++j) s += (double)gp_w[h*10 + j];
    gpw_mean[h] = s / 10.0;
    if (h == 0) {
        double sb = 0.0;
        #pragma unroll
        for (int j = 0; j < 10; ++j) sb += (double)gp_b[j];
        gpw_mean[HALFD] = sb / 10.0;           // gpb_mean at [512]
    }
}

// ---------------- K1: copy first half + low dot (fp64 accumulate) ----------------
__global__ __launch_bounds__(256) void k_copy_low(
        const float* __restrict__ src, const double* __restrict__ gpw_mean,
        float* __restrict__ out, double* __restrict__ low) {
    int wave = (blockIdx.x * 256 + threadIdx.x) >> 6;   // one wave per row
    int lane = threadIdx.x & 63;
    const float4* s4 = reinterpret_cast<const float4*>(src + (size_t)wave * DMODEL);
    float4 c0 = s4[lane];
    float4 c1 = s4[lane + 64];
    float4* o4 = reinterpret_cast<float4*>(out + (size_t)wave * DMODEL);
    o4[lane]      = c0;
    o4[lane + 64] = c1;
    float4 x0 = s4[128 + lane];
    float4 x1 = s4[192 + lane];
    const double* g0 = gpw_mean + lane*4;
    const double* g1 = gpw_mean + 256 + lane*4;
    double d = (double)x0.x*g0[0] + (double)x0.y*g0[1] + (double)x0.z*g0[2] + (double)x0.w*g0[3]
             + (double)x1.x*g1[0] + (double)x1.y*g1[1] + (double)x1.z*g1[2] + (double)x1.w*g1[3];
    #pragma unroll
    for (int o = 32; o; o >>= 1) d += __shfl_xor(d, o);
    if (lane == 0) low[wave] = d + gpw_mean[HALFD];
}

// ---------------- fused: top-64 (blocks 0..63) + logits GEMM (blocks 64..) ----------------
union SharedU {
    struct { float xsT[64][68]; float wsm[64][68]; } g;                  // 34816 B
    struct { unsigned long long ky[KIDX(PNUM-1)+1];
             unsigned short id[KIDX(PNUM-1)+1];
             double lowp[PLEN]; } t;                                     // ~46.4 KB
};

__global__ __launch_bounds__(256) void k_logits_topk(
        const float* __restrict__ src, const float* __restrict__ fw,
        const float* __restrict__ pool, const double* __restrict__ low,
        float* __restrict__ part, int* __restrict__ sel, int nks) {
    __shared__ SharedU u;
    int t = threadIdx.x;
    if (blockIdx.x < 64) {
        // ---------------- top-k role: scores + padded bitonic sort ----------------
        int p = blockIdx.x;
        if (t < PLEN) u.t.lowp[t] = low[p*PLEN + t];   // batch-0 rows
        __syncthreads();
        #pragma unroll
        for (int q = 0; q < 16; ++q) {
            int n = q*256 + t;
            const float4* p4 = reinterpret_cast<const float4*>(pool + (size_t)n*PLEN);
            double s = 0.0;
            #pragma unroll
            for (int r = 0; r < 8; ++r) {
                float4 v = p4[r];
                s += (double)v.x*u.t.lowp[r*4] + (double)v.y*u.t.lowp[r*4+1]
                   + (double)v.z*u.t.lowp[r*4+2] + (double)v.w*u.t.lowp[r*4+3];
            }
            unsigned long long ub = (unsigned long long)__double_as_longlong(s);
            unsigned long long key = ub ^ (((unsigned long long)((long long)ub >> 63)) | 0x8000000000000000ULL);
            u.t.ky[KIDX(n)] = key;
            u.t.id[KIDX(n)] = (unsigned short)n;
        }
        __syncthreads();
        for (int kk = 2; kk <= PNUM; kk <<= 1) {
            for (int j = kk >> 1; j > 0; j >>= 1) {
                #pragma unroll
                for (int e = 0; e < 8; ++e) {
                    int pi = e*256 + t;                        // 2048 disjoint pairs
                    int i  = ((pi & ~(j-1)) << 1) | (pi & (j-1));
                    int x  = i | j;
                    int ii = KIDX(i), xx = KIDX(x);
                    unsigned long long ka = u.t.ky[ii], kb = u.t.ky[xx];
                    unsigned short ia = u.t.id[ii], ib = u.t.id[xx];
                    bool up = (i & kk) == 0;
                    bool a_first = (ka > kb) || (ka == kb && ia < ib);
                    bool sw = up ? !a_first : a_first;
                    if (sw) {
                        u.t.ky[ii] = kb; u.t.ky[xx] = ka;
                        u.t.id[ii] = ib; u.t.id[xx] = ia;
                    }
                }
                __syncthreads();
            }
        }
        if (t < SIM) sel[p*SIM + t] = (int)u.t.id[KIDX(t)];
    } else {
        // ---------------- logits role: 64 rows x K-chunk, reg double-buffered ----------------
        int g = blockIdx.x - 64;
        int mt = g / nks, ks = g - mt*nks;
        int r0 = mt * 64;
        int kchunk = KDIM / nks;
        int nstep = kchunk >> 6;
        int ty = t >> 4, tx = t & 15;
        float acc[4][4] = {};
        float4 xr[4], wr[4];
        int jw = t >> 2;                 // w row for this thread
        // prefetch step 0
        {
            int k0 = ks*kchunk;
            int l = k0 >> 9, h0 = k0 & 511;
            #pragma unroll
            for (int q = 0; q < 4; ++q) {
                int f = t + q*256; int i = f >> 4, kq = f & 15;
                int R = r0 + i; int b = R >> 6, p = R & 63;
                xr[q] = *reinterpret_cast<const float4*>(
                    src + ((size_t)(b*SEQ + p*PLEN + l))*DMODEL + HALFD + h0 + kq*4);
                wr[q] = *reinterpret_cast<const float4*>(
                    fw + (size_t)(k0 + jw)*SIM + ((t&3) + q*4)*4);
            }
        }
        for (int step = 0; step < nstep; ++step) {
            // write prefetched regs to LDS
            #pragma unroll
            for (int q = 0; q < 4; ++q) {
                int f = t + q*256; int i = f >> 4, kq = f & 15;
                u.g.xsT[kq*4+0][i] = xr[q].x;
                u.g.xsT[kq*4+1][i] = xr[q].y;
                u.g.xsT[kq*4+2][i] = xr[q].z;
                u.g.xsT[kq*4+3][i] = xr[q].w;
                *reinterpret_cast<float4*>(&u.g.wsm[jw][((t&3) + q*4)*4]) = wr[q];
            }
            __syncthreads();
            if (step + 1 < nstep) {       // prefetch next step (overlaps compute)
                int k0 = ks*kchunk + (step+1)*64;
                int l = k0 >> 9, h0 = k0 & 511;
                #pragma unroll
                for (int q = 0; q < 4; ++q) {
                    int f = t + q*256; int i = f >> 4, kq = f & 15;
                    int R = r0 + i; int b = R >> 6, p = R & 63;
                    xr[q] = *reinterpret_cast<const float4*>(
                        src + ((size_t)(b*SEQ + p*PLEN + l))*DMODEL + HALFD + h0 + kq*4);
                    wr[q] = *reinterpret_cast<const float4*>(
                        fw + (size_t)(k0 + jw)*SIM + ((t&3) + q*4)*4);
                }
            }
            #pragma unroll 8
            for (int k = 0; k < 64; ++k) {
                float4 av = *reinterpret_cast<float4*>(&u.g.xsT[k][ty*4]);
                float4 wv = *reinterpret_cast<float4*>(&u.g.wsm[k][tx*4]);
                acc[0][0] += av.x*wv.x; acc[0][1] += av.x*wv.y; acc[0][2] += av.x*wv.z; acc[0][3] += av.x*wv.w;
                acc[1][0] += av.y*wv.x; acc[1][1] += av.y*wv.y; acc[1][2] += av.y*wv.z; acc[1][3] += av.y*wv.w;
                acc[2][0] += av.z*wv.x; acc[2][1] += av.z*wv.y; acc[2][2] += av.z*wv.z; acc[2][3] += av.z*wv.w;
                acc[3][0] += av.w*wv.x; acc[3][1] += av.w*wv.y; acc[3][2] += av.w*wv.z; acc[3][3] += av.w*wv.w;
            }
            __syncthreads();
        }
        float* pp = part + (size_t)(mt*nks + ks) * 4096;
        #pragma unroll
        for (int i = 0; i < 4; ++i) {
            float4 v = { acc[i][0], acc[i][1], acc[i][2], acc[i][3] };
            *reinterpret_cast<float4*>(pp + (ty*4 + i)*64 + tx*4) = v;
        }
    }
}

// ---------------- K4: reduce partials + bias + softmax -> route ----------------
__global__ __launch_bounds__(64) void k_softmax(
        const float* __restrict__ part, const float* __restrict__ fb,
        float* __restrict__ route, int nks) {
    int row = blockIdx.x;             // b*64+p
    int s = threadIdx.x;              // 0..63
    int mt = row >> 6, i = row & 63;
    float v = fb[s];
    for (int ks = 0; ks < nks; ++ks)
        v += part[(size_t)(mt*nks + ks)*4096 + i*64 + s];
    float m = v;
    #pragma unroll
    for (int o = 32; o; o >>= 1) m = fmaxf(m, __shfl_xor(m, o));
    float e = expf(v - m);
    float sum = e;
    #pragma unroll
    for (int o = 32; o; o >>= 1) sum += __shfl_xor(sum, o);
    route[row*64 + s] = e / sum;
}

// ---------------- K5: fuse + recover GEMM + padding + zeros ----------------
__global__ __launch_bounds__(256) void k_out(
        const float* __restrict__ route, const int* __restrict__ sel,
        const float* __restrict__ pool, const float* __restrict__ rw,
        const float* __restrict__ rb, float* __restrict__ out, float* __restrict__ pad) {
    __shared__ float A_T[SIM][36];           // [s][l], pad 36
    __shared__ float rws[64][132];           // 128-col chunk of recover_w (+pad)
    __shared__ float routeS[64];
    int row = blockIdx.x;                    // b*64+p
    int b = row >> 6, p = row & 63;
    int t = threadIdx.x;
    if (t < 64) routeS[t] = route[row*64 + t];
    __syncthreads();
    #pragma unroll
    for (int q = 0; q < 8; ++q) {            // A_T[s][l] = route[s]*pool[sel[p,s]][l]
        int e = t + q*256;
        int s = e >> 5, l = e & 31;
        A_T[s][l] = routeS[s] * pool[(size_t)sel[p*SIM + s]*PLEN + l];
    }
    __syncthreads();
    if (t < 32) {                            // padding row-sum
        float ps = 0.f;
        #pragma unroll
        for (int s = 0; s < 64; ++s) ps += A_T[s][t];
        pad[(size_t)b*2*SEQ + SEQ + p*PLEN + t] = ps;
    } else if (t < 64) {                     // zeros in first half of padding_out
        pad[(size_t)b*2*SEQ + p*PLEN + (t - 32)] = 0.f;
    }
    int l0  = (t >> 5) * 4;
    int h04 = (t & 31) * 4;
    for (int hc = 0; hc < HALFD; hc += 128) {
        #pragma unroll
        for (int q = 0; q < 8; ++q) {        // stage recover_w[:, hc:hc+128]
            int fi = t + q*256;
            int r = fi >> 5, c4 = fi & 31;
            float4 v = *reinterpret_cast<const float4*>(rw + (size_t)r*HALFD + hc + c4*4);
            *reinterpret_cast<float4*>(&rws[r][c4*4]) = v;
        }
        __syncthreads();
        float acc[4][4] = {};
        #pragma unroll 8
        for (int s = 0; s < 64; ++s) {
            float4 av = *reinterpret_cast<float4*>(&A_T[s][l0]);
            float4 wv = *reinterpret_cast<float4*>(&rws[s][h04]);
            acc[0][0] += av.x*wv.x; acc[0][1] += av.x*wv.y; acc[0][2] += av.x*wv.z; acc[0][3] += av.x*wv.w;
            acc[1][0] += av.y*wv.x; acc[1][1] += av.y*wv.y; acc[1][2] += av.y*wv.z; acc[1][3] += av.y*wv.w;
            acc[2][0] += av.z*wv.x; acc[2][1] += av.z*wv.y; acc[2][2] += av.z*wv.z; acc[2][3] += av.z*wv.w;
            acc[3][0] += av.w*wv.x; acc[3][1] += av.w*wv.y; acc[3][2] += av.w*wv.z; acc[3][3] += av.w*wv.w;
        }
        int h = hc + h04;
        float4 bias = *reinterpret_cast<const float4*>(rb + h);
        #pragma unroll
        for (int i = 0; i < 4; ++i) {
            int l = l0 + i;
            float4 v = { acc[i][0] + bias.x, acc[i][1] + bias.y,
                         acc[i][2] + bias.z, acc[i][3] + bias.w };
            *reinterpret_cast<float4*>(out + ((size_t)(b*SEQ + p*PLEN + l))*DMODEL + HALFD + h) = v;
        }
        __syncthreads();
    }
}

static const void* by_size(void* const* d_in, const int* in_sizes, int n_in,
                           int want, int fallback) {
    for (int i = 0; i < n_in; ++i) if (in_sizes[i] == want) return d_in[i];
    return d_in[fallback];
}

extern "C" void kernel_launch(void* const* d_in, const int* in_sizes, int n_in,
                              void* d_out, int out_size, void* d_ws, size_t ws_size,
                              hipStream_t stream) {
    const float* src  = (const float*)by_size(d_in, in_sizes, n_in, NB*SEQ*DMODEL, 0);
    const float* pool = (const float*)by_size(d_in, in_sizes, n_in, PNUM*PLEN, 1);
    const float* fw   = (const float*)by_size(d_in, in_sizes, n_in, KDIM*SIM, 2);
    const float* fb   = (const float*)by_size(d_in, in_sizes, n_in, SIM, 3);
    const float* rw   = (const float*)by_size(d_in, in_sizes, n_in, SIM*HALFD, 4);
    const float* rb   = (const float*)by_size(d_in, in_sizes, n_in, HALFD, 5);
    const float* gpw  = (const float*)by_size(d_in, in_sizes, n_in, HALFD*10, 6);
    const float* gpb  = (const float*)by_size(d_in, in_sizes, n_in, 10, 7);
    float* out = (float*)d_out;
    float* pad = out + OUT0;

    // KSPLIT: 32 if workspace allows (part = 8 MB), else 8 (proven footprint)
    int nks = (ws_size >= (12u << 20)) ? 32 : 8;

    double* gpw_mean = (double*)d_ws;                       // 8 KB
    double* low      = gpw_mean + 1024;                     // 256 KB
    int*    sel      = (int*)(low + 32768);                 // 16 KB
    float*  route    = (float*)(sel + 4096);                // 256 KB
    float*  part     = route + MROWS*SIM;                   // nks * 256 KB

    hipLaunchKernelGGL(k_prep,        dim3(1),           dim3(512), 0, stream, gpw, gpb, gpw_mean);
    hipLaunchKernelGGL(k_copy_low,    dim3(NROWS/4),     dim3(256), 0, stream, src, gpw_mean, out, low);
    hipLaunchKernelGGL(k_logits_topk, dim3(64 + 16*nks), dim3(256), 0, stream, src, fw, pool, low, part, sel, nks);
    hipLaunchKernelGGL(k_softmax,     dim3(MROWS),       dim3(64),  0, stream, part, fb, route, nks);
    hipLaunchKernelGGL(k_out,         dim3(MROWS),       dim3(256), 0, stream, route, sel, pool, rw, rb, out, pad);
}

// Round 8
// 155.166 us; speedup vs baseline: 2.0371x; 1.2562x over previous
//
#include <hip/hip_runtime.h>
#include <hip/hip_bf16.h>

#define NB 16
#define DMODEL 1024
#define HALFD 512
#define PNUM 4096
#define PLEN 32
#define SEQ 2048
#define SIM 64
#define NPATCH 64
#define NROWS (NB*SEQ)        // 32768 sequence rows
#define MROWS (NB*NPATCH)     // 1024 (b,p) rows
#define KDIM (PLEN*HALFD)     // 16384
#define OUT0 ((size_t)NB*SEQ*DMODEL)
#define SLOT(e) ((e) + ((e) >> 3))   // skewed LDS slot: stride 9 -> ~4-way max conflicts

// ---------------- K0: gp_w row means + gp_b mean (fp64) ----------------
__global__ void k_prep(const float* __restrict__ gp_w, const float* __restrict__ gp_b,
                       double* __restrict__ gpw_mean) {
    int h = threadIdx.x;                       // 512 threads
    double s = 0.0;
    #pragma unroll
    for (int j = 0; j < 10; ++j) s += (double)gp_w[h*10 + j];
    gpw_mean[h] = s / 10.0;
    if (h == 0) {
        double sb = 0.0;
        #pragma unroll
        for (int j = 0; j < 10; ++j) sb += (double)gp_b[j];
        gpw_mean[HALFD] = sb / 10.0;           // gpb_mean at [512]
    }
}

// ---------------- K1: copy first half + low dot (fp64 accumulate) ----------------
__global__ __launch_bounds__(256) void k_copy_low(
        const float* __restrict__ src, const double* __restrict__ gpw_mean,
        float* __restrict__ out, double* __restrict__ low) {
    int wave = (blockIdx.x * 256 + threadIdx.x) >> 6;   // one wave per row
    int lane = threadIdx.x & 63;
    const float4* s4 = reinterpret_cast<const float4*>(src + (size_t)wave * DMODEL);
    float4 c0 = s4[lane];
    float4 c1 = s4[lane + 64];
    float4* o4 = reinterpret_cast<float4*>(out + (size_t)wave * DMODEL);
    o4[lane]      = c0;
    o4[lane + 64] = c1;
    float4 x0 = s4[128 + lane];
    float4 x1 = s4[192 + lane];
    const double* g0 = gpw_mean + lane*4;
    const double* g1 = gpw_mean + 256 + lane*4;
    double d = (double)x0.x*g0[0] + (double)x0.y*g0[1] + (double)x0.z*g0[2] + (double)x0.w*g0[3]
             + (double)x1.x*g1[0] + (double)x1.y*g1[1] + (double)x1.z*g1[2] + (double)x1.w*g1[3];
    #pragma unroll
    for (int o = 32; o; o >>= 1) d += __shfl_xor(d, o);
    if (lane == 0) low[wave] = d + gpw_mean[HALFD];
}

// ---------------- fused: topk phase-1 (blocks 0..255) + logits GEMM (blocks 256..) ----------------
// Phase-1: block (p,q) scores patterns n in [q*1024, q*1024+1024), packs
// (orderable_key & ~0xFFF) | (0xFFF - n) into one u64 (idx-embedded, exact-tie
// -> lowest idx), full bitonic sort desc of 1024 in skewed LDS, emits top 64.
union SharedU {
    struct { float xsT[64][68]; float wsm[64][68]; } g;                    // 34816 B
    struct { unsigned long long ky[SLOT(1023)+1]; double lowp[PLEN]; } t;  // 9.4 KB
};

__global__ __launch_bounds__(256) void k_logits_topk(
        const float* __restrict__ src, const float* __restrict__ fw,
        const float* __restrict__ pool, const double* __restrict__ low,
        float* __restrict__ part, unsigned long long* __restrict__ cand, int nks) {
    __shared__ SharedU u;
    int t = threadIdx.x;
    if (blockIdx.x < 256) {
        // ---------------- top-k phase-1 ----------------
        int p = blockIdx.x >> 2, q = blockIdx.x & 3;
        if (t < PLEN) u.t.lowp[t] = low[p*PLEN + t];   // batch-0 rows
        __syncthreads();
        #pragma unroll
        for (int c = 0; c < 4; ++c) {
            int e = c*256 + t;                         // local 0..1023
            int n = q*1024 + e;
            const float4* p4 = reinterpret_cast<const float4*>(pool + (size_t)n*PLEN);
            double s = 0.0;
            #pragma unroll
            for (int r = 0; r < 8; ++r) {
                float4 v = p4[r];
                s += (double)v.x*u.t.lowp[r*4] + (double)v.y*u.t.lowp[r*4+1]
                   + (double)v.z*u.t.lowp[r*4+2] + (double)v.w*u.t.lowp[r*4+3];
            }
            unsigned long long ub = (unsigned long long)__double_as_longlong(s);
            unsigned long long okey = ub ^ (((unsigned long long)((long long)ub >> 63)) | 0x8000000000000000ULL);
            u.t.ky[SLOT(e)] = (okey & ~0xFFFULL) | (unsigned long long)(0xFFF - n);
        }
        __syncthreads();
        for (int kk = 2; kk <= 1024; kk <<= 1) {
            for (int j = kk >> 1; j > 0; j >>= 1) {
                #pragma unroll
                for (int e2 = 0; e2 < 2; ++e2) {
                    int pi = e2*256 + t;                       // 512 disjoint pairs
                    int i  = ((pi & ~(j-1)) << 1) | (pi & (j-1));
                    int x  = i | j;
                    int si = SLOT(i), sx = SLOT(x);
                    unsigned long long a = u.t.ky[si], b = u.t.ky[sx];
                    bool up = (i & kk) == 0;                   // descending sort
                    if (up ? (b > a) : (a > b)) { u.t.ky[si] = b; u.t.ky[sx] = a; }
                }
                __syncthreads();
            }
        }
        if (t < SIM) cand[(size_t)(p*4 + q)*SIM + t] = u.t.ky[SLOT(t)];
    } else {
        // ---------------- logits role: 64 rows x K-chunk, reg double-buffered ----------------
        int g = blockIdx.x - 256;
        int mt = g / nks, ks = g - mt*nks;
        int r0 = mt * 64;
        int kchunk = KDIM / nks;
        int nstep = kchunk >> 6;
        int ty = t >> 4, tx = t & 15;
        float acc[4][4] = {};
        float4 xr[4], wr[4];
        int jw = t >> 2;
        {   // prefetch step 0
            int k0 = ks*kchunk;
            int l = k0 >> 9, h0 = k0 & 511;
            #pragma unroll
            for (int q = 0; q < 4; ++q) {
                int f = t + q*256; int i = f >> 4, kq = f & 15;
                int R = r0 + i; int b = R >> 6, p = R & 63;
                xr[q] = *reinterpret_cast<const float4*>(
                    src + ((size_t)(b*SEQ + p*PLEN + l))*DMODEL + HALFD + h0 + kq*4);
                wr[q] = *reinterpret_cast<const float4*>(
                    fw + (size_t)(k0 + jw)*SIM + ((t&3) + q*4)*4);
            }
        }
        for (int step = 0; step < nstep; ++step) {
            #pragma unroll
            for (int q = 0; q < 4; ++q) {
                int f = t + q*256; int i = f >> 4, kq = f & 15;
                u.g.xsT[kq*4+0][i] = xr[q].x;
                u.g.xsT[kq*4+1][i] = xr[q].y;
                u.g.xsT[kq*4+2][i] = xr[q].z;
                u.g.xsT[kq*4+3][i] = xr[q].w;
                *reinterpret_cast<float4*>(&u.g.wsm[jw][((t&3) + q*4)*4]) = wr[q];
            }
            __syncthreads();
            if (step + 1 < nstep) {
                int k0 = ks*kchunk + (step+1)*64;
                int l = k0 >> 9, h0 = k0 & 511;
                #pragma unroll
                for (int q = 0; q < 4; ++q) {
                    int f = t + q*256; int i = f >> 4, kq = f & 15;
                    int R = r0 + i; int b = R >> 6, p = R & 63;
                    xr[q] = *reinterpret_cast<const float4*>(
                        src + ((size_t)(b*SEQ + p*PLEN + l))*DMODEL + HALFD + h0 + kq*4);
                    wr[q] = *reinterpret_cast<const float4*>(
                        fw + (size_t)(k0 + jw)*SIM + ((t&3) + q*4)*4);
                }
            }
            #pragma unroll 8
            for (int k = 0; k < 64; ++k) {
                float4 av = *reinterpret_cast<float4*>(&u.g.xsT[k][ty*4]);
                float4 wv = *reinterpret_cast<float4*>(&u.g.wsm[k][tx*4]);
                acc[0][0] += av.x*wv.x; acc[0][1] += av.x*wv.y; acc[0][2] += av.x*wv.z; acc[0][3] += av.x*wv.w;
                acc[1][0] += av.y*wv.x; acc[1][1] += av.y*wv.y; acc[1][2] += av.y*wv.z; acc[1][3] += av.y*wv.w;
                acc[2][0] += av.z*wv.x; acc[2][1] += av.z*wv.y; acc[2][2] += av.z*wv.z; acc[2][3] += av.z*wv.w;
                acc[3][0] += av.w*wv.x; acc[3][1] += av.w*wv.y; acc[3][2] += av.w*wv.z; acc[3][3] += av.w*wv.w;
            }
            __syncthreads();
        }
        float* pp = part + (size_t)(mt*nks + ks) * 4096;
        #pragma unroll
        for (int i = 0; i < 4; ++i) {
            float4 v = { acc[i][0], acc[i][1], acc[i][2], acc[i][3] };
            *reinterpret_cast<float4*>(pp + (ty*4 + i)*64 + tx*4) = v;
        }
    }
}

// ---------------- K4: softmax (blocks 0..1023) + topk phase-2 merge (blocks 1024..1087) ----------------
__global__ __launch_bounds__(64) void k_softmax(
        const float* __restrict__ part, const float* __restrict__ fb,
        float* __restrict__ route, const unsigned long long* __restrict__ cand,
        int* __restrict__ sel, int nks) {
    if (blockIdx.x < MROWS) {
        int row = blockIdx.x;             // b*64+p
        int s = threadIdx.x;              // 0..63
        int mt = row >> 6, i = row & 63;
        float v = fb[s];
        for (int ks = 0; ks < nks; ++ks)
            v += part[(size_t)(mt*nks + ks)*4096 + i*64 + s];
        float m = v;
        #pragma unroll
        for (int o = 32; o; o >>= 1) m = fmaxf(m, __shfl_xor(m, o));
        float e = expf(v - m);
        float sum = e;
        #pragma unroll
        for (int o = 32; o; o >>= 1) sum += __shfl_xor(sum, o);
        route[row*64 + s] = e / sum;
    } else {
        // merge 4 sorted 64-lists -> top 64 (sort 256 packed keys desc)
        __shared__ unsigned long long m[SLOT(255)+1];
        int p = blockIdx.x - MROWS;
        int t = threadIdx.x;
        #pragma unroll
        for (int c = 0; c < 4; ++c) {
            int e = c*64 + t;
            m[SLOT(e)] = cand[(size_t)p*256 + e];
        }
        __syncthreads();
        for (int kk = 2; kk <= 256; kk <<= 1) {
            for (int j = kk >> 1; j > 0; j >>= 1) {
                #pragma unroll
                for (int e2 = 0; e2 < 2; ++e2) {
                    int pi = e2*64 + t;                        // 128 disjoint pairs
                    int i  = ((pi & ~(j-1)) << 1) | (pi & (j-1));
                    int x  = i | j;
                    int si = SLOT(i), sx = SLOT(x);
                    unsigned long long a = m[si], b = m[sx];
                    bool up = (i & kk) == 0;
                    if (up ? (b > a) : (a > b)) { m[si] = b; m[sx] = a; }
                }
                __syncthreads();
            }
        }
        sel[p*SIM + t] = 0xFFF - (int)(m[SLOT(t)] & 0xFFFULL);
    }
}

// ---------------- K5: fuse + recover GEMM + padding + zeros ----------------
__global__ __launch_bounds__(256) void k_out(
        const float* __restrict__ route, const int* __restrict__ sel,
        const float* __restrict__ pool, const float* __restrict__ rw,
        const float* __restrict__ rb, float* __restrict__ out, float* __restrict__ pad) {
    __shared__ float A_T[SIM][36];           // [s][l], pad 36
    __shared__ float rws[64][132];           // 128-col chunk of recover_w (+pad)
    __shared__ float routeS[64];
    int row = blockIdx.x;                    // b*64+p
    int b = row >> 6, p = row & 63;
    int t = threadIdx.x;
    if (t < 64) routeS[t] = route[row*64 + t];
    __syncthreads();
    #pragma unroll
    for (int q = 0; q < 8; ++q) {            // A_T[s][l] = route[s]*pool[sel[p,s]][l]
        int e = t + q*256;
        int s = e >> 5, l = e & 31;
        A_T[s][l] = routeS[s] * pool[(size_t)sel[p*SIM + s]*PLEN + l];
    }
    __syncthreads();
    if (t < 32) {                            // padding row-sum
        float ps = 0.f;
        #pragma unroll
        for (int s = 0; s < 64; ++s) ps += A_T[s][t];
        pad[(size_t)b*2*SEQ + SEQ + p*PLEN + t] = ps;
    } else if (t < 64) {                     // zeros in first half of padding_out
        pad[(size_t)b*2*SEQ + p*PLEN + (t - 32)] = 0.f;
    }
    int l0  = (t >> 5) * 4;
    int h04 = (t & 31) * 4;
    for (int hc = 0; hc < HALFD; hc += 128) {
        #pragma unroll
        for (int q = 0; q < 8; ++q) {        // stage recover_w[:, hc:hc+128]
            int fi = t + q*256;
            int r = fi >> 5, c4 = fi & 31;
            float4 v = *reinterpret_cast<const float4*>(rw + (size_t)r*HALFD + hc + c4*4);
            *reinterpret_cast<float4*>(&rws[r][c4*4]) = v;
        }
        __syncthreads();
        float acc[4][4] = {};
        #pragma unroll 8
        for (int s = 0; s < 64; ++s) {
            float4 av = *reinterpret_cast<float4*>(&A_T[s][l0]);
            float4 wv = *reinterpret_cast<float4*>(&rws[s][h04]);
            acc[0][0] += av.x*wv.x; acc[0][1] += av.x*wv.y; acc[0][2] += av.x*wv.z; acc[0][3] += av.x*wv.w;
            acc[1][0] += av.y*wv.x; acc[1][1] += av.y*wv.y; acc[1][2] += av.y*wv.z; acc[1][3] += av.y*wv.w;
            acc[2][0] += av.z*wv.x; acc[2][1] += av.z*wv.y; acc[2][2] += av.z*wv.z; acc[2][3] += av.z*wv.w;
            acc[3][0] += av.w*wv.x; acc[3][1] += av.w*wv.y; acc[3][2] += av.w*wv.z; acc[3][3] += av.w*wv.w;
        }
        int h = hc + h04;
        float4 bias = *reinterpret_cast<const float4*>(rb + h);
        #pragma unroll
        for (int i = 0; i < 4; ++i) {
            int l = l0 + i;
            float4 v = { acc[i][0] + bias.x, acc[i][1] + bias.y,
                         acc[i][2] + bias.z, acc[i][3] + bias.w };
            *reinterpret_cast<float4*>(out + ((size_t)(b*SEQ + p*PLEN + l))*DMODEL + HALFD + h) = v;
        }
        __syncthreads();
    }
}

static const void* by_size(void* const* d_in, const int* in_sizes, int n_in,
                           int want, int fallback) {
    for (int i = 0; i < n_in; ++i) if (in_sizes[i] == want) return d_in[i];
    return d_in[fallback];
}

extern "C" void kernel_launch(void* const* d_in, const int* in_sizes, int n_in,
                              void* d_out, int out_size, void* d_ws, size_t ws_size,
                              hipStream_t stream) {
    const float* src  = (const float*)by_size(d_in, in_sizes, n_in, NB*SEQ*DMODEL, 0);
    const float* pool = (const float*)by_size(d_in, in_sizes, n_in, PNUM*PLEN, 1);
    const float* fw   = (const float*)by_size(d_in, in_sizes, n_in, KDIM*SIM, 2);
    const float* fb   = (const float*)by_size(d_in, in_sizes, n_in, SIM, 3);
    const float* rw   = (const float*)by_size(d_in, in_sizes, n_in, SIM*HALFD, 4);
    const float* rb   = (const float*)by_size(d_in, in_sizes, n_in, HALFD, 5);
    const float* gpw  = (const float*)by_size(d_in, in_sizes, n_in, HALFD*10, 6);
    const float* gpb  = (const float*)by_size(d_in, in_sizes, n_in, 10, 7);
    float* out = (float*)d_out;
    float* pad = out + OUT0;

    int nks = (ws_size >= (12u << 20)) ? 32 : 8;

    double* gpw_mean = (double*)d_ws;                              // 8 KB
    double* low      = gpw_mean + 1024;                            // 256 KB
    unsigned long long* cand = (unsigned long long*)(low + 32768); // 128 KB
    int*    sel      = (int*)(cand + NPATCH*4*SIM);                // 16 KB
    float*  route    = (float*)(sel + 4096);                       // 256 KB
    float*  part     = route + MROWS*SIM;                          // nks*256 KB

    hipLaunchKernelGGL(k_prep,        dim3(1),            dim3(512), 0, stream, gpw, gpb, gpw_mean);
    hipLaunchKernelGGL(k_copy_low,    dim3(NROWS/4),      dim3(256), 0, stream, src, gpw_mean, out, low);
    hipLaunchKernelGGL(k_logits_topk, dim3(256 + 16*nks), dim3(256), 0, stream, src, fw, pool, low, part, cand, nks);
    hipLaunchKernelGGL(k_softmax,     dim3(MROWS+NPATCH), dim3(64),  0, stream, part, fb, route, cand, sel, nks);
    hipLaunchKernelGGL(k_out,         dim3(MROWS),        dim3(256), 0, stream, route, sel, pool, rw, rb, out, pad);
}

// Round 9
// 144.936 us; speedup vs baseline: 2.1809x; 1.0706x over previous
//
#include <hip/hip_runtime.h>
#include <hip/hip_bf16.h>

#define NB 16
#define DMODEL 1024
#define HALFD 512
#define PNUM 4096
#define PLEN 32
#define SEQ 2048
#define SIM 64
#define NPATCH 64
#define NROWS (NB*SEQ)        // 32768 sequence rows
#define MROWS (NB*NPATCH)     // 1024 (b,p) rows
#define KDIM (PLEN*HALFD)     // 16384
#define OUT0 ((size_t)NB*SEQ*DMODEL)
#define SLOT(e) ((e) + ((e) >> 3))
#define NTOPK 512
#define NCOPY 1024

typedef __attribute__((ext_vector_type(8))) short s8v;          // 8 bf16 (4 VGPR)
typedef __attribute__((ext_vector_type(4))) float f32x4;
typedef __attribute__((ext_vector_type(8))) unsigned short ush8;

__device__ __forceinline__ unsigned short f2bf(float f) {
    __hip_bfloat16 h = __float2bfloat16(f);
    return *reinterpret_cast<unsigned short*>(&h);
}
__device__ __forceinline__ float bf2f(unsigned short u) {
    __hip_bfloat16 h = *reinterpret_cast<__hip_bfloat16*>(&u);
    return __bfloat162float(h);
}

// ---------------- K0: gp means (block 0) + fw -> fwT bf16 hi/lo transpose (blocks 1..256) ----------------
__global__ __launch_bounds__(256) void k_prep(
        const float* __restrict__ gp_w, const float* __restrict__ gp_b,
        const float* __restrict__ fw, double* __restrict__ gpw_mean,
        unsigned short* __restrict__ fwT_hi, unsigned short* __restrict__ fwT_lo) {
    int t = threadIdx.x;
    if (blockIdx.x == 0) {
        for (int h = t; h < HALFD; h += 256) {
            double s = 0.0;
            #pragma unroll
            for (int j = 0; j < 10; ++j) s += (double)gp_w[h*10 + j];
            gpw_mean[h] = s / 10.0;
        }
        if (t == 0) {
            double sb = 0.0;
            #pragma unroll
            for (int j = 0; j < 10; ++j) sb += (double)gp_b[j];
            gpw_mean[HALFD] = sb / 10.0;
        }
    } else {
        __shared__ float tile[64][68];
        int k0 = (blockIdx.x - 1) * 64;
        int i = t >> 2;
        #pragma unroll
        for (int q = 0; q < 4; ++q) {
            int c = (t & 3) + q*4;
            float4 v = *reinterpret_cast<const float4*>(fw + (size_t)(k0 + i)*SIM + c*4);
            *reinterpret_cast<float4*>(&tile[i][c*4]) = v;
        }
        __syncthreads();
        int n = t & 63, half = t >> 6;
        ush8 hv[2], lv[2];
        #pragma unroll
        for (int g2 = 0; g2 < 2; ++g2) {
            #pragma unroll
            for (int j = 0; j < 8; ++j) {
                float f = tile[half*16 + g2*8 + j][n];
                unsigned short hb = f2bf(f);
                hv[g2][j] = hb;
                lv[g2][j] = f2bf(f - bf2f(hb));
            }
        }
        size_t off = (size_t)n*KDIM + k0 + half*16;
        *reinterpret_cast<ush8*>(fwT_hi + off)     = hv[0];
        *reinterpret_cast<ush8*>(fwT_hi + off + 8) = hv[1];
        *reinterpret_cast<ush8*>(fwT_lo + off)     = lv[0];
        *reinterpret_cast<ush8*>(fwT_lo + off + 8) = lv[1];
    }
}

// ---------------- mega-kernel: topk p1 (0..511) | logits MFMA (512..512+16*nks) | copy ----------------
__global__ __launch_bounds__(256) void k_main(
        const float* __restrict__ src, const float* __restrict__ pool,
        const unsigned short* __restrict__ fwT_hi, const unsigned short* __restrict__ fwT_lo,
        const double* __restrict__ gpw_mean,
        float* __restrict__ part, unsigned long long* __restrict__ cand,
        float* __restrict__ out, int nks) {
    int bid = blockIdx.x, t = threadIdx.x;
    int lane = t & 63, w = t >> 6;
    if (bid < NTOPK) {
        // ---- top-k phase 1: patch p, chunk q of 512 patterns; own lowp ----
        __shared__ unsigned long long ky[SLOT(511)+1];
        __shared__ double lowp[PLEN];
        int p = bid >> 3, q = bid & 7;
        const double* g0 = gpw_mean + lane*4;
        const double* g1 = gpw_mean + 256 + lane*4;
        #pragma unroll
        for (int rr = 0; rr < 8; ++rr) {
            int r = w*8 + rr;
            const float4* s4 = reinterpret_cast<const float4*>(src + ((size_t)(p*PLEN + r))*DMODEL + HALFD);
            float4 x0 = s4[lane], x1 = s4[lane + 64];
            double d = (double)x0.x*g0[0] + (double)x0.y*g0[1] + (double)x0.z*g0[2] + (double)x0.w*g0[3]
                     + (double)x1.x*g1[0] + (double)x1.y*g1[1] + (double)x1.z*g1[2] + (double)x1.w*g1[3];
            #pragma unroll
            for (int o = 32; o; o >>= 1) d += __shfl_xor(d, o);
            if (lane == 0) lowp[r] = d + gpw_mean[HALFD];
        }
        __syncthreads();
        #pragma unroll
        for (int c = 0; c < 2; ++c) {
            int e = c*256 + t;
            int n = q*512 + e;
            const float4* p4 = reinterpret_cast<const float4*>(pool + (size_t)n*PLEN);
            double s = 0.0;
            #pragma unroll
            for (int r2 = 0; r2 < 8; ++r2) {
                float4 v = p4[r2];
                s += (double)v.x*lowp[r2*4] + (double)v.y*lowp[r2*4+1]
                   + (double)v.z*lowp[r2*4+2] + (double)v.w*lowp[r2*4+3];
            }
            unsigned long long ub = (unsigned long long)__double_as_longlong(s);
            unsigned long long okey = ub ^ (((unsigned long long)((long long)ub >> 63)) | 0x8000000000000000ULL);
            ky[SLOT(e)] = (okey & ~0xFFFULL) | (unsigned long long)(0xFFF - n);
        }
        __syncthreads();
        for (int kk = 2; kk <= 512; kk <<= 1) {
            for (int j = kk >> 1; j > 0; j >>= 1) {
                int i  = ((t & ~(j-1)) << 1) | (t & (j-1));   // 256 disjoint pairs
                int x  = i | j;
                int si = SLOT(i), sx = SLOT(x);
                unsigned long long a = ky[si], b = ky[sx];
                bool up = (i & kk) == 0;
                if (up ? (b > a) : (a > b)) { ky[si] = b; ky[sx] = a; }
                __syncthreads();
            }
        }
        if (t < SIM) cand[(size_t)(p*8 + q)*SIM + t] = ky[SLOT(t)];
    } else if (bid < NTOPK + 16*nks) {
        // ---- logits: MFMA split-bf16, all operands global->reg, no LDS ----
        int g = bid - NTOPK;
        int mt = g / nks, ks = g - mt*nks;
        int kchunk = KDIM / nks, nstep = kchunk >> 6;
        int r0 = mt*64;
        int ml = lane & 15, kg = lane >> 4;
        int Rrow = r0 + w*16 + ml;
        int bb = Rrow >> 6, pp = Rrow & 63;
        const float* xrow = src + ((size_t)(bb*SEQ + pp*PLEN))*DMODEL + HALFD;
        f32x4 acc[4] = {};
        for (int step = 0; step < nstep; ++step) {
            int k0 = ks*kchunk + step*64;
            int l = k0 >> 9, h0 = k0 & 511;          // 64-chunk never crosses l
            const float* ap = xrow + (size_t)l*DMODEL + h0 + kg*8;
            float4 va0 = *reinterpret_cast<const float4*>(ap);
            float4 va1 = *reinterpret_cast<const float4*>(ap + 4);
            float4 vb0 = *reinterpret_cast<const float4*>(ap + 32);
            float4 vb1 = *reinterpret_cast<const float4*>(ap + 36);
            s8v ah0, al0, ah1, al1;
            float fa[8] = {va0.x,va0.y,va0.z,va0.w,va1.x,va1.y,va1.z,va1.w};
            float fbv[8] = {vb0.x,vb0.y,vb0.z,vb0.w,vb1.x,vb1.y,vb1.z,vb1.w};
            #pragma unroll
            for (int j = 0; j < 8; ++j) {
                unsigned short hb = f2bf(fa[j]);
                ah0[j] = (short)hb;
                al0[j] = (short)f2bf(fa[j] - bf2f(hb));
                unsigned short hb2 = f2bf(fbv[j]);
                ah1[j] = (short)hb2;
                al1[j] = (short)f2bf(fbv[j] - bf2f(hb2));
            }
            #pragma unroll
            for (int fn = 0; fn < 4; ++fn) {
                size_t nrow = (size_t)(fn*16 + ml)*KDIM + k0 + kg*8;
                s8v bh0 = *reinterpret_cast<const s8v*>(fwT_hi + nrow);
                s8v bl0 = *reinterpret_cast<const s8v*>(fwT_lo + nrow);
                s8v bh1 = *reinterpret_cast<const s8v*>(fwT_hi + nrow + 32);
                s8v bl1 = *reinterpret_cast<const s8v*>(fwT_lo + nrow + 32);
                acc[fn] = __builtin_amdgcn_mfma_f32_16x16x32_bf16(ah0, bh0, acc[fn], 0, 0, 0);
                acc[fn] = __builtin_amdgcn_mfma_f32_16x16x32_bf16(ah0, bl0, acc[fn], 0, 0, 0);
                acc[fn] = __builtin_amdgcn_mfma_f32_16x16x32_bf16(al0, bh0, acc[fn], 0, 0, 0);
                acc[fn] = __builtin_amdgcn_mfma_f32_16x16x32_bf16(ah1, bh1, acc[fn], 0, 0, 0);
                acc[fn] = __builtin_amdgcn_mfma_f32_16x16x32_bf16(ah1, bl1, acc[fn], 0, 0, 0);
                acc[fn] = __builtin_amdgcn_mfma_f32_16x16x32_bf16(al1, bh1, acc[fn], 0, 0, 0);
            }
        }
        float* ppart = part + (size_t)(mt*nks + ks)*4096;
        #pragma unroll
        for (int fn = 0; fn < 4; ++fn)
            #pragma unroll
            for (int r = 0; r < 4; ++r)
                ppart[(w*16 + kg*4 + r)*64 + fn*16 + ml] = acc[fn][r];
    } else {
        // ---- copy role: out[:, :512] = src[:, :512] ----
        int cb = bid - (NTOPK + 16*nks);
        size_t total = (size_t)NROWS * 128;
        const float4* s4 = reinterpret_cast<const float4*>(src);
        float4* o4 = reinterpret_cast<float4*>(out);
        for (size_t idx = (size_t)cb*256 + t; idx < total; idx += (size_t)NCOPY*256) {
            size_t r = idx >> 7, c = idx & 127;
            o4[r*256 + c] = s4[r*256 + c];
        }
    }
}

// ---------------- softmax (0..1023) + topk phase-2 merge of 8 lists (1024..1087) ----------------
__global__ __launch_bounds__(64) void k_softmax(
        const float* __restrict__ part, const float* __restrict__ fb,
        float* __restrict__ route, const unsigned long long* __restrict__ cand,
        int* __restrict__ sel, int nks) {
    if (blockIdx.x < MROWS) {
        int row = blockIdx.x;
        int s = threadIdx.x;
        int mt = row >> 6, i = row & 63;
        float v = fb[s];
        for (int ks = 0; ks < nks; ++ks)
            v += part[(size_t)(mt*nks + ks)*4096 + i*64 + s];
        float m = v;
        #pragma unroll
        for (int o = 32; o; o >>= 1) m = fmaxf(m, __shfl_xor(m, o));
        float e = expf(v - m);
        float sum = e;
        #pragma unroll
        for (int o = 32; o; o >>= 1) sum += __shfl_xor(sum, o);
        route[row*64 + s] = e / sum;
    } else {
        __shared__ unsigned long long m[SLOT(511)+1];
        int p = blockIdx.x - MROWS;
        int t = threadIdx.x;
        #pragma unroll
        for (int c = 0; c < 8; ++c) {
            int e = c*64 + t;
            m[SLOT(e)] = cand[(size_t)p*512 + e];
        }
        __syncthreads();
        for (int kk = 2; kk <= 512; kk <<= 1) {
            for (int j = kk >> 1; j > 0; j >>= 1) {
                #pragma unroll
                for (int e2 = 0; e2 < 4; ++e2) {
                    int pi = e2*64 + t;
                    int i  = ((pi & ~(j-1)) << 1) | (pi & (j-1));
                    int x  = i | j;
                    int si = SLOT(i), sx = SLOT(x);
                    unsigned long long a = m[si], b = m[sx];
                    bool up = (i & kk) == 0;
                    if (up ? (b > a) : (a > b)) { m[si] = b; m[sx] = a; }
                }
                __syncthreads();
            }
        }
        sel[p*SIM + t] = 0xFFF - (int)(m[SLOT(t)] & 0xFFFULL);
    }
}

// ---------------- K5: fuse + recover GEMM + padding + zeros ----------------
__global__ __launch_bounds__(256) void k_out(
        const float* __restrict__ route, const int* __restrict__ sel,
        const float* __restrict__ pool, const float* __restrict__ rw,
        const float* __restrict__ rb, float* __restrict__ out, float* __restrict__ pad) {
    __shared__ float A_T[SIM][36];
    __shared__ float rws[64][132];
    __shared__ float routeS[64];
    int row = blockIdx.x;
    int b = row >> 6, p = row & 63;
    int t = threadIdx.x;
    if (t < 64) routeS[t] = route[row*64 + t];
    __syncthreads();
    #pragma unroll
    for (int q = 0; q < 8; ++q) {
        int e = t + q*256;
        int s = e >> 5, l = e & 31;
        A_T[s][l] = routeS[s] * pool[(size_t)sel[p*SIM + s]*PLEN + l];
    }
    __syncthreads();
    if (t < 32) {
        float ps = 0.f;
        #pragma unroll
        for (int s = 0; s < 64; ++s) ps += A_T[s][t];
        pad[(size_t)b*2*SEQ + SEQ + p*PLEN + t] = ps;
    } else if (t < 64) {
        pad[(size_t)b*2*SEQ + p*PLEN + (t - 32)] = 0.f;
    }
    int l0  = (t >> 5) * 4;
    int h04 = (t & 31) * 4;
    for (int hc = 0; hc < HALFD; hc += 128) {
        #pragma unroll
        for (int q = 0; q < 8; ++q) {
            int fi = t + q*256;
            int r = fi >> 5, c4 = fi & 31;
            float4 v = *reinterpret_cast<const float4*>(rw + (size_t)r*HALFD + hc + c4*4);
            *reinterpret_cast<float4*>(&rws[r][c4*4]) = v;
        }
        __syncthreads();
        float acc[4][4] = {};
        #pragma unroll 8
        for (int s = 0; s < 64; ++s) {
            float4 av = *reinterpret_cast<float4*>(&A_T[s][l0]);
            float4 wv = *reinterpret_cast<float4*>(&rws[s][h04]);
            acc[0][0] += av.x*wv.x; acc[0][1] += av.x*wv.y; acc[0][2] += av.x*wv.z; acc[0][3] += av.x*wv.w;
            acc[1][0] += av.y*wv.x; acc[1][1] += av.y*wv.y; acc[1][2] += av.y*wv.z; acc[1][3] += av.y*wv.w;
            acc[2][0] += av.z*wv.x; acc[2][1] += av.z*wv.y; acc[2][2] += av.z*wv.z; acc[2][3] += av.z*wv.w;
            acc[3][0] += av.w*wv.x; acc[3][1] += av.w*wv.y; acc[3][2] += av.w*wv.z; acc[3][3] += av.w*wv.w;
        }
        int h = hc + h04;
        float4 bias = *reinterpret_cast<const float4*>(rb + h);
        #pragma unroll
        for (int i = 0; i < 4; ++i) {
            int l = l0 + i;
            float4 v = { acc[i][0] + bias.x, acc[i][1] + bias.y,
                         acc[i][2] + bias.z, acc[i][3] + bias.w };
            *reinterpret_cast<float4*>(out + ((size_t)(b*SEQ + p*PLEN + l))*DMODEL + HALFD + h) = v;
        }
        __syncthreads();
    }
}

static const void* by_size(void* const* d_in, const int* in_sizes, int n_in,
                           int want, int fallback) {
    for (int i = 0; i < n_in; ++i) if (in_sizes[i] == want) return d_in[i];
    return d_in[fallback];
}

extern "C" void kernel_launch(void* const* d_in, const int* in_sizes, int n_in,
                              void* d_out, int out_size, void* d_ws, size_t ws_size,
                              hipStream_t stream) {
    const float* src  = (const float*)by_size(d_in, in_sizes, n_in, NB*SEQ*DMODEL, 0);
    const float* pool = (const float*)by_size(d_in, in_sizes, n_in, PNUM*PLEN, 1);
    const float* fw   = (const float*)by_size(d_in, in_sizes, n_in, KDIM*SIM, 2);
    const float* fb   = (const float*)by_size(d_in, in_sizes, n_in, SIM, 3);
    const float* rw   = (const float*)by_size(d_in, in_sizes, n_in, SIM*HALFD, 4);
    const float* rb   = (const float*)by_size(d_in, in_sizes, n_in, HALFD, 5);
    const float* gpw  = (const float*)by_size(d_in, in_sizes, n_in, HALFD*10, 6);
    const float* gpb  = (const float*)by_size(d_in, in_sizes, n_in, 10, 7);
    float* out = (float*)d_out;
    float* pad = out + OUT0;

    int nks = (ws_size >= (size_t)(13u << 20)) ? 32 : 8;

    double* gpw_mean = (double*)d_ws;                                   // 8 KB
    unsigned short* fwT_hi = (unsigned short*)(gpw_mean + 1024);        // 2 MB
    unsigned short* fwT_lo = fwT_hi + (size_t)SIM*KDIM;                 // 2 MB
    unsigned long long* cand = (unsigned long long*)(fwT_lo + (size_t)SIM*KDIM); // 256 KB
    int*   sel   = (int*)(cand + (size_t)NPATCH*512);                   // 16 KB
    float* route = (float*)(sel + 4096);                                // 256 KB
    float* part  = route + MROWS*SIM;                                   // nks * 256 KB

    hipLaunchKernelGGL(k_prep, dim3(257), dim3(256), 0, stream, gpw, gpb, fw, gpw_mean, fwT_hi, fwT_lo);
    hipLaunchKernelGGL(k_main, dim3(NTOPK + 16*nks + NCOPY), dim3(256), 0, stream,
                       src, pool, fwT_hi, fwT_lo, gpw_mean, part, cand, out, nks);
    hipLaunchKernelGGL(k_softmax, dim3(MROWS + NPATCH), dim3(64), 0, stream, part, fb, route, cand, sel, nks);
    hipLaunchKernelGGL(k_out, dim3(MROWS), dim3(256), 0, stream, route, sel, pool, rw, rb, out, pad);
}

// Round 10
// 139.281 us; speedup vs baseline: 2.2694x; 1.0406x over previous
//
#include <hip/hip_runtime.h>
#include <hip/hip_bf16.h>

#define NB 16
#define DMODEL 1024
#define HALFD 512
#define PNUM 4096
#define PLEN 32
#define SEQ 2048
#define SIM 64
#define NPATCH 64
#define NROWS (NB*SEQ)        // 32768 sequence rows
#define MROWS (NB*NPATCH)     // 1024 (b,p) rows
#define KDIM (PLEN*HALFD)     // 16384
#define OUT0 ((size_t)NB*SEQ*DMODEL)

typedef __attribute__((ext_vector_type(8))) short s8v;          // 8 bf16 (4 VGPR)
typedef __attribute__((ext_vector_type(4))) float f32x4;
typedef __attribute__((ext_vector_type(8))) unsigned short ush8;
typedef unsigned long long u64;

__device__ __forceinline__ unsigned short f2bf(float f) {
    __hip_bfloat16 h = __float2bfloat16(f);
    return *reinterpret_cast<unsigned short*>(&h);
}
__device__ __forceinline__ float bf2f(unsigned short u) {
    __hip_bfloat16 h = *reinterpret_cast<__hip_bfloat16*>(&u);
    return __bfloat162float(h);
}
__device__ __forceinline__ u64 umax64(u64 a, u64 b) { return a > b ? a : b; }
__device__ __forceinline__ u64 umin64(u64 a, u64 b) { return a < b ? a : b; }
// descending clean pass over a bitonic sequence (one value per lane)
__device__ __forceinline__ u64 clean6(u64 v, int lane) {
    #pragma unroll
    for (int j = 32; j; j >>= 1) {
        u64 o = __shfl_xor(v, j);
        v = ((lane & j) == 0) ? umax64(v, o) : umin64(v, o);
    }
    return v;
}

// ---------------- K0: gp means (block 0) + fw -> fwT bf16 hi/lo transpose ----------------
__global__ __launch_bounds__(256) void k_prep(
        const float* __restrict__ gp_w, const float* __restrict__ gp_b,
        const float* __restrict__ fw, double* __restrict__ gpw_mean,
        unsigned short* __restrict__ fwT_hi, unsigned short* __restrict__ fwT_lo) {
    int t = threadIdx.x;
    if (blockIdx.x == 0) {
        for (int h = t; h < HALFD; h += 256) {
            double s = 0.0;
            #pragma unroll
            for (int j = 0; j < 10; ++j) s += (double)gp_w[h*10 + j];
            gpw_mean[h] = s / 10.0;
        }
        if (t == 0) {
            double sb = 0.0;
            #pragma unroll
            for (int j = 0; j < 10; ++j) sb += (double)gp_b[j];
            gpw_mean[HALFD] = sb / 10.0;
        }
    } else {
        __shared__ float tile[64][68];
        int k0 = (blockIdx.x - 1) * 64;
        int i = t >> 2;
        #pragma unroll
        for (int q = 0; q < 4; ++q) {
            int c = (t & 3) + q*4;
            float4 v = *reinterpret_cast<const float4*>(fw + (size_t)(k0 + i)*SIM + c*4);
            *reinterpret_cast<float4*>(&tile[i][c*4]) = v;
        }
        __syncthreads();
        int n = t & 63, half = t >> 6;
        ush8 hv[2], lv[2];
        #pragma unroll
        for (int g2 = 0; g2 < 2; ++g2) {
            #pragma unroll
            for (int j = 0; j < 8; ++j) {
                float f = tile[half*16 + g2*8 + j][n];
                unsigned short hb = f2bf(f);
                hv[g2][j] = hb;
                lv[g2][j] = f2bf(f - bf2f(hb));
            }
        }
        size_t off = (size_t)n*KDIM + k0 + half*16;
        *reinterpret_cast<ush8*>(fwT_hi + off)     = hv[0];
        *reinterpret_cast<ush8*>(fwT_hi + off + 8) = hv[1];
        *reinterpret_cast<ush8*>(fwT_lo + off)     = lv[0];
        *reinterpret_cast<ush8*>(fwT_lo + off + 8) = lv[1];
    }
}

// ---------------- K1: low[r] for batch-0 rows only (fp64) ----------------
__global__ __launch_bounds__(256) void k_low(
        const float* __restrict__ src, const double* __restrict__ gpw_mean,
        double* __restrict__ low) {
    int r = (blockIdx.x * 256 + threadIdx.x) >> 6;     // 0..2047 (batch 0)
    int lane = threadIdx.x & 63;
    const float4* s4 = reinterpret_cast<const float4*>(src + (size_t)r * DMODEL);
    float4 x0 = s4[128 + lane];
    float4 x1 = s4[192 + lane];
    const double* g0 = gpw_mean + lane*4;
    const double* g1 = gpw_mean + 256 + lane*4;
    double d = (double)x0.x*g0[0] + (double)x0.y*g0[1] + (double)x0.z*g0[2] + (double)x0.w*g0[3]
             + (double)x1.x*g1[0] + (double)x1.y*g1[1] + (double)x1.z*g1[2] + (double)x1.w*g1[3];
    #pragma unroll
    for (int o = 32; o; o >>= 1) d += __shfl_xor(d, o);
    if (lane == 0) low[r] = d + gpw_mean[HALFD];
}

// ---------------- K2: topk — wave-register bitonic, no barriers in sort ----------------
// block (p,q): 512 patterns; wave w sorts chunks 2w,2w+1 (64 each, in regs via
// shfl), merges to its top-64; wave 0 merges the 4 wave lists -> cand[p*8+q].
__global__ __launch_bounds__(256) void k_topk(
        const double* __restrict__ low, const float* __restrict__ pool,
        u64* __restrict__ cand) {
    __shared__ double lowp[PLEN];
    __shared__ u64 wl[4][64];
    int t = threadIdx.x, lane = t & 63, w = t >> 6;
    int p = blockIdx.x >> 3, q = blockIdx.x & 7;
    if (t < PLEN) lowp[t] = low[p*PLEN + t];
    __syncthreads();
    u64 v[2];
    #pragma unroll
    for (int cc = 0; cc < 2; ++cc) {
        int n = q*512 + (w*2 + cc)*64 + lane;
        const float4* p4 = reinterpret_cast<const float4*>(pool + (size_t)n*PLEN);
        double s = 0.0;
        #pragma unroll
        for (int r2 = 0; r2 < 8; ++r2) {
            float4 vv = p4[r2];
            s += (double)vv.x*lowp[r2*4] + (double)vv.y*lowp[r2*4+1]
               + (double)vv.z*lowp[r2*4+2] + (double)vv.w*lowp[r2*4+3];
        }
        u64 ub = (u64)__double_as_longlong(s);
        u64 okey = ub ^ (((u64)((long long)ub >> 63)) | 0x8000000000000000ULL);
        v[cc] = (okey & ~0xFFFULL) | (u64)(0xFFF - n);
    }
    // descending bitonic sort of each chunk across lanes (21 shfl steps)
    #pragma unroll
    for (int kk = 2; kk <= 64; kk <<= 1) {
        #pragma unroll
        for (int j = kk >> 1; j; j >>= 1) {
            #pragma unroll
            for (int cc = 0; cc < 2; ++cc) {
                u64 o = __shfl_xor(v[cc], j);
                bool keepMax = ((lane & kk) == 0) == ((lane & j) == 0);
                v[cc] = keepMax ? umax64(v[cc], o) : umin64(v[cc], o);
            }
        }
    }
    // merge the wave's two desc lists -> top-64
    u64 rb = __shfl(v[1], 63 - lane);
    u64 m = umax64(v[0], rb);
    m = clean6(m, lane);
    wl[w][lane] = m;
    __syncthreads();
    if (w == 0) {
        u64 a = umax64(wl[0][lane], wl[1][63 - lane]);
        a = clean6(a, lane);
        u64 b = umax64(wl[2][lane], wl[3][63 - lane]);
        b = clean6(b, lane);
        u64 r2 = __shfl(b, 63 - lane);
        u64 f = umax64(a, r2);
        f = clean6(f, lane);
        cand[(size_t)(p*8 + q)*SIM + lane] = f;
    }
}

// ---------------- K3: logits MFMA split-bf16, operands global->reg, no LDS ----------------
__global__ __launch_bounds__(256) void k_logits(
        const float* __restrict__ src,
        const unsigned short* __restrict__ fwT_hi, const unsigned short* __restrict__ fwT_lo,
        float* __restrict__ part, int nks) {
    int t = threadIdx.x, lane = t & 63, w = t >> 6;
    int g = blockIdx.x;
    int mt = g / nks, ks = g - mt*nks;
    int kchunk = KDIM / nks, nstep = kchunk >> 6;
    int r0 = mt*64;
    int ml = lane & 15, kg = lane >> 4;
    int Rrow = r0 + w*16 + ml;
    int bb = Rrow >> 6, pp = Rrow & 63;
    const float* xrow = src + ((size_t)(bb*SEQ + pp*PLEN))*DMODEL + HALFD;
    f32x4 acc[4] = {};
    for (int step = 0; step < nstep; ++step) {
        int k0 = ks*kchunk + step*64;
        int l = k0 >> 9, h0 = k0 & 511;          // 64-chunk never crosses l
        const float* ap = xrow + (size_t)l*DMODEL + h0 + kg*8;
        float4 va0 = *reinterpret_cast<const float4*>(ap);
        float4 va1 = *reinterpret_cast<const float4*>(ap + 4);
        float4 vb0 = *reinterpret_cast<const float4*>(ap + 32);
        float4 vb1 = *reinterpret_cast<const float4*>(ap + 36);
        s8v ah0, al0, ah1, al1;
        float fa[8] = {va0.x,va0.y,va0.z,va0.w,va1.x,va1.y,va1.z,va1.w};
        float fbv[8] = {vb0.x,vb0.y,vb0.z,vb0.w,vb1.x,vb1.y,vb1.z,vb1.w};
        #pragma unroll
        for (int j = 0; j < 8; ++j) {
            unsigned short hb = f2bf(fa[j]);
            ah0[j] = (short)hb;
            al0[j] = (short)f2bf(fa[j] - bf2f(hb));
            unsigned short hb2 = f2bf(fbv[j]);
            ah1[j] = (short)hb2;
            al1[j] = (short)f2bf(fbv[j] - bf2f(hb2));
        }
        #pragma unroll
        for (int fn = 0; fn < 4; ++fn) {
            size_t nrow = (size_t)(fn*16 + ml)*KDIM + k0 + kg*8;
            s8v bh0 = *reinterpret_cast<const s8v*>(fwT_hi + nrow);
            s8v bl0 = *reinterpret_cast<const s8v*>(fwT_lo + nrow);
            s8v bh1 = *reinterpret_cast<const s8v*>(fwT_hi + nrow + 32);
            s8v bl1 = *reinterpret_cast<const s8v*>(fwT_lo + nrow + 32);
            acc[fn] = __builtin_amdgcn_mfma_f32_16x16x32_bf16(ah0, bh0, acc[fn], 0, 0, 0);
            acc[fn] = __builtin_amdgcn_mfma_f32_16x16x32_bf16(ah0, bl0, acc[fn], 0, 0, 0);
            acc[fn] = __builtin_amdgcn_mfma_f32_16x16x32_bf16(al0, bh0, acc[fn], 0, 0, 0);
            acc[fn] = __builtin_amdgcn_mfma_f32_16x16x32_bf16(ah1, bh1, acc[fn], 0, 0, 0);
            acc[fn] = __builtin_amdgcn_mfma_f32_16x16x32_bf16(ah1, bl1, acc[fn], 0, 0, 0);
            acc[fn] = __builtin_amdgcn_mfma_f32_16x16x32_bf16(al1, bh1, acc[fn], 0, 0, 0);
        }
    }
    float* ppart = part + (size_t)(mt*nks + ks)*4096;
    #pragma unroll
    for (int fn = 0; fn < 4; ++fn)
        #pragma unroll
        for (int r = 0; r < 4; ++r)
            ppart[(w*16 + kg*4 + r)*64 + fn*16 + ml] = acc[fn][r];
}

// ---------------- K4: copy first halves ----------------
__global__ __launch_bounds__(256) void k_copy(
        const float* __restrict__ src, float* __restrict__ out) {
    size_t total = (size_t)NROWS * 128;
    const float4* s4 = reinterpret_cast<const float4*>(src);
    float4* o4 = reinterpret_cast<float4*>(out);
    for (size_t idx = (size_t)blockIdx.x*256 + threadIdx.x; idx < total; idx += (size_t)2048*256) {
        size_t r = idx >> 7, c = idx & 127;
        o4[r*256 + c] = s4[r*256 + c];
    }
}

// ---------------- K5: softmax (0..1023) + topk final merge via wave-bitonic (1024..1087) ----------------
__global__ __launch_bounds__(64) void k_softmax(
        const float* __restrict__ part, const float* __restrict__ fb,
        float* __restrict__ route, const u64* __restrict__ cand,
        int* __restrict__ sel, int nks) {
    if (blockIdx.x < MROWS) {
        int row = blockIdx.x;
        int s = threadIdx.x;
        int mt = row >> 6, i = row & 63;
        float v = fb[s];
        for (int ks = 0; ks < nks; ++ks)
            v += part[(size_t)(mt*nks + ks)*4096 + i*64 + s];
        float m = v;
        #pragma unroll
        for (int o = 32; o; o >>= 1) m = fmaxf(m, __shfl_xor(m, o));
        float e = expf(v - m);
        float sum = e;
        #pragma unroll
        for (int o = 32; o; o >>= 1) sum += __shfl_xor(sum, o);
        route[row*64 + s] = e / sum;
    } else {
        int p = blockIdx.x - MROWS;
        int lane = threadIdx.x;
        const u64* c = cand + (size_t)p*8*SIM;
        u64 a = umax64(c[lane],         c[1*SIM + 63 - lane]); a = clean6(a, lane);
        u64 b = umax64(c[2*SIM + lane], c[3*SIM + 63 - lane]); b = clean6(b, lane);
        u64 d = umax64(c[4*SIM + lane], c[5*SIM + 63 - lane]); d = clean6(d, lane);
        u64 e = umax64(c[6*SIM + lane], c[7*SIM + 63 - lane]); e = clean6(e, lane);
        u64 ab = umax64(a, __shfl(b, 63 - lane)); ab = clean6(ab, lane);
        u64 de = umax64(d, __shfl(e, 63 - lane)); de = clean6(de, lane);
        u64 f  = umax64(ab, __shfl(de, 63 - lane)); f = clean6(f, lane);
        sel[p*SIM + lane] = 0xFFF - (int)(f & 0xFFFULL);
    }
}

// ---------------- K6: fuse + recover GEMM + padding + zeros ----------------
__global__ __launch_bounds__(256) void k_out(
        const float* __restrict__ route, const int* __restrict__ sel,
        const float* __restrict__ pool, const float* __restrict__ rw,
        const float* __restrict__ rb, float* __restrict__ out, float* __restrict__ pad) {
    __shared__ float A_T[SIM][36];
    __shared__ float rws[64][132];
    __shared__ float routeS[64];
    int row = blockIdx.x;
    int b = row >> 6, p = row & 63;
    int t = threadIdx.x;
    if (t < 64) routeS[t] = route[row*64 + t];
    __syncthreads();
    #pragma unroll
    for (int q = 0; q < 8; ++q) {
        int e = t + q*256;
        int s = e >> 5, l = e & 31;
        A_T[s][l] = routeS[s] * pool[(size_t)sel[p*SIM + s]*PLEN + l];
    }
    __syncthreads();
    if (t < 32) {
        float ps = 0.f;
        #pragma unroll
        for (int s = 0; s < 64; ++s) ps += A_T[s][t];
        pad[(size_t)b*2*SEQ + SEQ + p*PLEN + t] = ps;
    } else if (t < 64) {
        pad[(size_t)b*2*SEQ + p*PLEN + (t - 32)] = 0.f;
    }
    int l0  = (t >> 5) * 4;
    int h04 = (t & 31) * 4;
    for (int hc = 0; hc < HALFD; hc += 128) {
        #pragma unroll
        for (int q = 0; q < 8; ++q) {
            int fi = t + q*256;
            int r = fi >> 5, c4 = fi & 31;
            float4 v = *reinterpret_cast<const float4*>(rw + (size_t)r*HALFD + hc + c4*4);
            *reinterpret_cast<float4*>(&rws[r][c4*4]) = v;
        }
        __syncthreads();
        float acc[4][4] = {};
        #pragma unroll 8
        for (int s = 0; s < 64; ++s) {
            float4 av = *reinterpret_cast<float4*>(&A_T[s][l0]);
            float4 wv = *reinterpret_cast<float4*>(&rws[s][h04]);
            acc[0][0] += av.x*wv.x; acc[0][1] += av.x*wv.y; acc[0][2] += av.x*wv.z; acc[0][3] += av.x*wv.w;
            acc[1][0] += av.y*wv.x; acc[1][1] += av.y*wv.y; acc[1][2] += av.y*wv.z; acc[1][3] += av.y*wv.w;
            acc[2][0] += av.z*wv.x; acc[2][1] += av.z*wv.y; acc[2][2] += av.z*wv.z; acc[2][3] += av.z*wv.w;
            acc[3][0] += av.w*wv.x; acc[3][1] += av.w*wv.y; acc[3][2] += av.w*wv.z; acc[3][3] += av.w*wv.w;
        }
        int h = hc + h04;
        float4 bias = *reinterpret_cast<const float4*>(rb + h);
        #pragma unroll
        for (int i = 0; i < 4; ++i) {
            int l = l0 + i;
            float4 v = { acc[i][0] + bias.x, acc[i][1] + bias.y,
                         acc[i][2] + bias.z, acc[i][3] + bias.w };
            *reinterpret_cast<float4*>(out + ((size_t)(b*SEQ + p*PLEN + l))*DMODEL + HALFD + h) = v;
        }
        __syncthreads();
    }
}

static const void* by_size(void* const* d_in, const int* in_sizes, int n_in,
                           int want, int fallback) {
    for (int i = 0; i < n_in; ++i) if (in_sizes[i] == want) return d_in[i];
    return d_in[fallback];
}

extern "C" void kernel_launch(void* const* d_in, const int* in_sizes, int n_in,
                              void* d_out, int out_size, void* d_ws, size_t ws_size,
                              hipStream_t stream) {
    const float* src  = (const float*)by_size(d_in, in_sizes, n_in, NB*SEQ*DMODEL, 0);
    const float* pool = (const float*)by_size(d_in, in_sizes, n_in, PNUM*PLEN, 1);
    const float* fw   = (const float*)by_size(d_in, in_sizes, n_in, KDIM*SIM, 2);
    const float* fb   = (const float*)by_size(d_in, in_sizes, n_in, SIM, 3);
    const float* rw   = (const float*)by_size(d_in, in_sizes, n_in, SIM*HALFD, 4);
    const float* rb   = (const float*)by_size(d_in, in_sizes, n_in, HALFD, 5);
    const float* gpw  = (const float*)by_size(d_in, in_sizes, n_in, HALFD*10, 6);
    const float* gpb  = (const float*)by_size(d_in, in_sizes, n_in, 10, 7);
    float* out = (float*)d_out;
    float* pad = out + OUT0;

    int nks = (ws_size >= (size_t)(14u << 20)) ? 32 : 8;

    double* gpw_mean = (double*)d_ws;                                   // 8 KB
    unsigned short* fwT_hi = (unsigned short*)(gpw_mean + 1024);        // 2 MB
    unsigned short* fwT_lo = fwT_hi + (size_t)SIM*KDIM;                 // 2 MB
    double* low = (double*)(fwT_lo + (size_t)SIM*KDIM);                 // 16 KB (2048 used)
    u64*   cand  = (u64*)(low + 2048);                                  // 256 KB
    int*   sel   = (int*)(cand + (size_t)NPATCH*8*SIM);                 // 16 KB
    float* route = (float*)(sel + 4096);                                // 256 KB
    float* part  = route + MROWS*SIM;                                   // nks * 256 KB

    hipLaunchKernelGGL(k_prep,    dim3(257),       dim3(256), 0, stream, gpw, gpb, fw, gpw_mean, fwT_hi, fwT_lo);
    hipLaunchKernelGGL(k_low,     dim3(512),       dim3(256), 0, stream, src, gpw_mean, low);
    hipLaunchKernelGGL(k_topk,    dim3(512),       dim3(256), 0, stream, low, pool, cand);
    hipLaunchKernelGGL(k_logits,  dim3(16*nks),    dim3(256), 0, stream, src, fwT_hi, fwT_lo, part, nks);
    hipLaunchKernelGGL(k_copy,    dim3(2048),      dim3(256), 0, stream, src, out);
    hipLaunchKernelGGL(k_softmax, dim3(MROWS+NPATCH), dim3(64), 0, stream, part, fb, route, cand, sel, nks);
    hipLaunchKernelGGL(k_out,     dim3(MROWS),     dim3(256), 0, stream, route, sel, pool, rw, rb, out, pad);
}